// Round 2
// 1214.656 us; speedup vs baseline: 1.0317x; 1.0317x over previous
//
#include <hip/hip_runtime.h>
#include <hip/hip_bf16.h>

typedef __bf16 bf16_t;
typedef __bf16 bf16x8 __attribute__((ext_vector_type(8)));
typedef float f32x4 __attribute__((ext_vector_type(4)));

static constexpr int B_ = 4, N_ = 4096, H_ = 4;
static constexpr int KS = 40;  // LDS k-stride (bf16): 80 B rows, 16B-aligned b128, 2-way max on reads

__device__ __forceinline__ f32x4 mfma_bf16(bf16x8 a, bf16x8 b, f32x4 c) {
  return __builtin_amdgcn_mfma_f32_16x16x32_bf16(a, b, c, 0, 0, 0);
}

// convert float4 -> 4 bf16 in registers, single 8 B LDS store (no scalar ds_write_b16)
__device__ __forceinline__ void stpk4(bf16_t* d, float4 v) {
  bf16_t t[4] = {(bf16_t)v.x, (bf16_t)v.y, (bf16_t)v.z, (bf16_t)v.w};
  *(uint2*)d = *(const uint2*)t;
}
__device__ __forceinline__ void stz8(bf16_t* d) { *(uint2*)d = make_uint2(0u, 0u); }

// kvsplit gather: quarter h, local col c (0..239) -> emb_all column
__device__ __forceinline__ int kvg(int h, int c) {
  if (c < 16)  return h * 16 + c;
  if (c < 48)  return 64 + h * 32 + c - 16;
  if (c < 112) return 192 + h * 64 + c - 48;
  return 448 + h * 128 + c - 112;
}

// ============ weight pre-convert fp32 -> bf16 (one pass, ~230k f4 items)
__global__ __launch_bounds__(256) void k_prep_w(
    const float* __restrict__ wk, const float* __restrict__ wv,
    const float* __restrict__ wkd, const float* __restrict__ wvd,
    const float* __restrict__ wo00, const float* __restrict__ wo01,
    const float* __restrict__ wo02, const float* __restrict__ wo03,
    const float* __restrict__ wo10, const float* __restrict__ wo11,
    const float* __restrict__ wo12, const float* __restrict__ wo13,
    bf16_t* __restrict__ Wkvb, bf16_t* __restrict__ Wob) {
  const float* wkv[4] = {wk, wv, wkd, wvd};
  const float* wo[2][4] = {{wo00, wo01, wo02, wo03}, {wo10, wo11, wo12, wo13}};
  const int soff_f4[5] = {0, 1024, 5120, 21504, 87040};
  for (int i = blockIdx.x * 256 + threadIdx.x; i < 231680; i += gridDim.x * 256) {
    if (i < 57600) {  // kv weights: 4 x 14400 f4
      int t = i / 14400, r = i - t * 14400;
      float4 v = *(const float4*)(wkv[t] + r * 4);
      stpk4(Wkvb + (size_t)t * 57600 + r * 4, v);
    } else {  // wout: 2 x 87040 f4
      int j = i - 57600;
      int mod = j / 87040, jr = j - mod * 87040;
      int s = (jr < 1024) ? 0 : (jr < 5120) ? 1 : (jr < 21504) ? 2 : 3;
      float4 v = *(const float4*)(wo[mod][s] + (jr - soff_f4[s]) * 4);
      stpk4(Wob + (size_t)mod * 348160 + jr * 4, v);
    }
  }
}

// ============ kvsplit prepass: emb_all fp32 [b,n,960] -> G bf16 [mod][bh][n][240]
// one 16B output chunk per item (8 cols; segments are multiples of 8 so no chunk crosses one)
__global__ __launch_bounds__(256) void k_kvsplit(
    const float* __restrict__ eA, const float* __restrict__ eB,
    bf16_t* __restrict__ G) {
  const int TOT = 2 * 16 * 4096 * 30;  // 3,932,160 chunks
  for (int i = blockIdx.x * 256 + threadIdx.x; i < TOT; i += gridDim.x * 256) {
    int t = i / 30;                 // row index: mod*65536 + bh*4096 + n
    int cg = i - t * 30;
    int mod = t >> 16;
    int row = t & 65535;            // bh*4096 + n
    int bh = row >> 12, n = row & 4095;
    int b = bh >> 2, h = bh & 3;
    int col = kvg(h, cg * 8);
    const float* src = (mod ? eB : eA) + ((size_t)b * N_ + n) * 960 + col;
    float4 v0 = *(const float4*)src;
    float4 v1 = *(const float4*)(src + 4);
    bf16_t o[8] = {(bf16_t)v0.x, (bf16_t)v0.y, (bf16_t)v0.z, (bf16_t)v0.w,
                   (bf16_t)v1.x, (bf16_t)v1.y, (bf16_t)v1.z, (bf16_t)v1.w};
    *(uint4*)(G + (size_t)t * 240 + cg * 8) = *(const uint4*)o;
  }
}

// ============ Q projection: Q[bh,n,d] -> written TRANSPOSED Qt[bh][d][4096] (packed uint2)
template <int C4>
__global__ __launch_bounds__(256) void k_proj_q(
    const float* __restrict__ e0, const float* __restrict__ w0, bf16_t* __restrict__ o0,
    const float* __restrict__ e1, const float* __restrict__ w1, bf16_t* __restrict__ o1) {
  constexpr int KP = (C4 < 32) ? 32 : C4;
  constexpr int NF = C4 / 16;
  const float* emb = blockIdx.z ? e1 : e0;
  const float* wq = blockIdx.z ? w1 : w0;
  bf16_t* qout = blockIdx.z ? o1 : o0;
  const int h = blockIdx.y;
  const int m0 = blockIdx.x * 128;
  const int b = m0 >> 12, n0 = m0 & 4095;
  const int tid = threadIdx.x, lane = tid & 63, wid = tid >> 6;
  const int l15 = lane & 15, q = lane >> 4;
  __shared__ bf16_t sA[128 * KS];
  __shared__ bf16_t sB[C4 * KS];
  const f32x4 fz = {0.f, 0.f, 0.f, 0.f};
  f32x4 acc[2][NF];
  for (int i = 0; i < 2; i++) for (int f = 0; f < NF; f++) acc[i][f] = fz;
  const float* srow = emb + ((size_t)b * N_ + n0) * (H_ * C4) + h * C4;
  const float* wb = wq + h * C4 * C4;
  for (int k0 = 0; k0 < KP; k0 += 32) {
    __syncthreads();
    for (int idx = tid; idx < 1024; idx += 256) {
      int r = idx >> 3, cg = idx & 7, c = k0 + cg * 4;
      if (c < C4) stpk4(&sA[r * KS + cg * 4], *(const float4*)(srow + (size_t)r * (H_ * C4) + c));
      else stz8(&sA[r * KS + cg * 4]);
    }
    for (int idx = tid; idx < C4 * 8; idx += 256) {
      int dd = idx >> 3, cg = idx & 7, c = k0 + cg * 4;
      if (c < C4) stpk4(&sB[dd * KS + cg * 4], *(const float4*)(wb + dd * C4 + c));
      else stz8(&sB[dd * KS + cg * 4]);
    }
    __syncthreads();
    const bf16_t* ap = &sA[(wid * 32 + l15) * KS + q * 8];
    bf16x8 a0 = *(const bf16x8*)ap;
    bf16x8 a1 = *(const bf16x8*)(ap + 16 * KS);
    for (int f = 0; f < NF; f++) {
      bf16x8 bb = *(const bf16x8*)&sB[(16 * f + l15) * KS + q * 8];
      acc[0][f] = mfma_bf16(a0, bb, acc[0][f]);
      acc[1][f] = mfma_bf16(a1, bb, acc[1][f]);
    }
  }
  // transposed write: Qt row c = 16f+l15, cols n = n0 + wid*32 + 16i + q*4 + r (4 packed)
  bf16_t* qbh = qout + (size_t)(b * H_ + h) * C4 * 4096;
  for (int i = 0; i < 2; i++)
    for (int f = 0; f < NF; f++) {
      bf16_t pk[4];
      for (int r = 0; r < 4; r++) pk[r] = (bf16_t)acc[i][f][r];
      *(uint2*)(qbh + (size_t)(16 * f + l15) * 4096 + n0 + wid * 32 + 16 * i + q * 4) =
          *(const uint2*)pk;
    }
}

// ============ K/V projection, merged per modality: one staged A tile feeds K and V MFMAs.
// A from pre-converted G (bf16, coalesced uint4). K stored transposed [bh][240][4096]; V n-major.
__global__ __launch_bounds__(256) void k_proj_kv(
    const bf16_t* __restrict__ G, const bf16_t* __restrict__ Wkvb,
    bf16_t* __restrict__ Kt0, bf16_t* __restrict__ V0,
    bf16_t* __restrict__ Kt1, bf16_t* __restrict__ V1) {
  const int mod = blockIdx.y;
  const bf16_t* src = G + (size_t)mod * ((size_t)B_ * H_ * N_ * 240);
  const bf16_t* wK = Wkvb + (size_t)(2 * mod) * 57600;
  const bf16_t* wV = Wkvb + (size_t)(2 * mod + 1) * 57600;
  bf16_t* Kt = mod ? Kt1 : Kt0;
  bf16_t* V = mod ? V1 : V0;
  const int m0 = blockIdx.x * 64;
  const int bh = m0 >> 12, n0 = m0 & 4095;
  const int tid = threadIdx.x, lane = tid & 63, wid = tid >> 6;
  const int l15 = lane & 15, q = lane >> 4;
  __shared__ bf16_t sA[64 * KS];
  __shared__ bf16_t sB[2][240 * KS];
  const f32x4 fz = {0.f, 0.f, 0.f, 0.f};
  f32x4 accK[15], accV[15];
  for (int f = 0; f < 15; f++) { accK[f] = fz; accV[f] = fz; }
  const bf16_t* arow = src + (size_t)m0 * 240;
  for (int k0 = 0; k0 < 256; k0 += 32) {
    __syncthreads();
    {  // A: 64 rows x 32 cols bf16 = 256 uint4, exactly 1 per thread
      int r = tid >> 2, g = tid & 3, c = k0 + g * 8;
      if (c < 240) *(uint4*)&sA[r * KS + g * 8] = *(const uint4*)(arow + (size_t)r * 240 + c);
      else *(uint4*)&sA[r * KS + g * 8] = make_uint4(0u, 0u, 0u, 0u);
    }
    for (int idx = tid; idx < 1920; idx += 256) {  // B: Wk and Wv tiles, uint4 (L2-resident)
      int m = idx >= 960;
      int j = idx - (m ? 960 : 0);
      int dd = j >> 2, g = j & 3, c = k0 + g * 8;
      const bf16_t* w = m ? wV : wK;
      if (c < 240) *(uint4*)&sB[m][dd * KS + g * 8] = *(const uint4*)(w + dd * 240 + c);
      else *(uint4*)&sB[m][dd * KS + g * 8] = make_uint4(0u, 0u, 0u, 0u);
    }
    __syncthreads();
    bf16x8 a = *(const bf16x8*)&sA[(wid * 16 + l15) * KS + q * 8];
#pragma unroll
    for (int f = 0; f < 15; f++) {
      bf16x8 bk = *(const bf16x8*)&sB[0][(16 * f + l15) * KS + q * 8];
      bf16x8 bv = *(const bf16x8*)&sB[1][(16 * f + l15) * KS + q * 8];
      accK[f] = mfma_bf16(a, bk, accK[f]);
      accV[f] = mfma_bf16(a, bv, accV[f]);
    }
  }
  // K^T: rows k=16f+l15, cols n (4 consecutive packed in b64)
  for (int f = 0; f < 15; f++) {
    bf16_t pk[4];
    for (int r = 0; r < 4; r++) pk[r] = (bf16_t)accK[f][r];
    bf16_t* dst = Kt + ((size_t)bh * 240 + 16 * f + l15) * 4096 + n0 + wid * 16 + q * 4;
    *(uint2*)dst = *(const uint2*)pk;
  }
  // V n-major
  bf16_t* orow = V + ((size_t)bh * N_ + n0) * 240;
  for (int f = 0; f < 15; f++)
    for (int r = 0; r < 4; r++) {
      int mm = wid * 16 + q * 4 + r;
      orow[(size_t)mm * 240 + 16 * f + l15] = (bf16_t)accV[f][r];
    }
}

// ============ scores: S[c,k] += (1/sqrt960) sum_{n chunk} Qt[c,n]*K^T[k,n]
// both operands staged via contiguous uint4 (Q now stored transposed)
template <int C4>
__global__ __launch_bounds__(256) void k_scores(
    const bf16_t* __restrict__ q0, const bf16_t* __restrict__ kt0, float* __restrict__ s0,
    const bf16_t* __restrict__ q1, const bf16_t* __restrict__ kt1, float* __restrict__ s1) {
  const int mod = blockIdx.z >> 3, chunk = blockIdx.z & 7;
  const bf16_t* qp = mod ? q1 : q0;
  const bf16_t* ktp = mod ? kt1 : kt0;
  float* sc = mod ? s1 : s0;
  const int bh = blockIdx.y;
  const int c0 = blockIdx.x * 16;
  const int tid = threadIdx.x, lane = tid & 63, wid = tid >> 6;
  const int l15 = lane & 15, q = lane >> 4;
  __shared__ bf16_t sQ[16 * KS];
  __shared__ bf16_t sK[240 * KS];
  const f32x4 fz = {0.f, 0.f, 0.f, 0.f};
  f32x4 acc[4] = {fz, fz, fz, fz};
  const bf16_t* ktb = ktp + (size_t)bh * 240 * 4096 + chunk * 512;
  const bf16_t* qb = qp + ((size_t)bh * C4 + c0) * 4096 + chunk * 512;
  for (int k0 = 0; k0 < 512; k0 += 32) {
    __syncthreads();
    if (tid < 64) {  // Q^T contiguous uint4 (16 c-rows x 32 n)
      int ci = tid >> 2, g = tid & 3;
      *(uint4*)&sQ[ci * KS + g * 8] = *(const uint4*)(qb + (size_t)ci * 4096 + k0 + g * 8);
    }
    for (int idx = tid; idx < 960; idx += 256) {  // K^T contiguous uint4
      int kk = idx >> 2, g = idx & 3;
      *(uint4*)&sK[kk * KS + g * 8] = *(const uint4*)(ktb + (size_t)kk * 4096 + k0 + g * 8);
    }
    __syncthreads();
    bf16x8 af = *(const bf16x8*)&sQ[l15 * KS + q * 8];
    for (int j = 0; j < 4; j++) {
      int f = wid + 4 * j;
      if (f < 15) {
        bf16x8 bb = *(const bf16x8*)&sK[(16 * f + l15) * KS + q * 8];
        acc[j] = mfma_bf16(af, bb, acc[j]);
      }
    }
  }
  const float rs = 0.0322748612183951f;  // 1/sqrt(960)
  float* sb = sc + (size_t)bh * C4 * 240;
  for (int j = 0; j < 4; j++) {
    int f = wid + 4 * j;
    if (f < 15)
      for (int r = 0; r < 4; r++)
        atomicAdd(&sb[(size_t)(c0 + q * 4 + r) * 240 + 16 * f + l15], acc[j][r] * rs);
  }
}

// ============ InstanceNorm over (c,k) per (b,h), then softmax over k (240)
__global__ __launch_bounds__(256) void k_inorm_softmax(float* __restrict__ p0,
                                                       float* __restrict__ p1, int c4) {
  float* p = (blockIdx.z ? p1 : p0) + (size_t)blockIdx.x * c4 * 240;
  const int tid = threadIdx.x;
  const int tot = c4 * 240;
  float s = 0.f, s2 = 0.f;
  for (int idx = tid; idx < tot; idx += 256) {
    float v = p[idx];
    s += v; s2 += v * v;
  }
#pragma unroll
  for (int off = 32; off > 0; off >>= 1) {
    s += __shfl_xor(s, off);
    s2 += __shfl_xor(s2, off);
  }
  __shared__ float rsum[4], rsum2[4], smv[2];
  const int wid = tid >> 6, lane = tid & 63;
  if (lane == 0) { rsum[wid] = s; rsum2[wid] = s2; }
  __syncthreads();
  if (tid == 0) {
    float ts = rsum[0] + rsum[1] + rsum[2] + rsum[3];
    float ts2 = rsum2[0] + rsum2[1] + rsum2[2] + rsum2[3];
    float mean = ts / tot;
    float var = ts2 / tot - mean * mean;
    smv[0] = mean; smv[1] = rsqrtf(var + 1e-5f);
  }
  __syncthreads();
  const float mean = smv[0], rstd = smv[1];
  for (int c = wid; c < c4; c += 4) {
    float* row = p + (size_t)c * 240;
    float x[4]; float mx = -1e30f;
#pragma unroll
    for (int t = 0; t < 4; t++) {
      int k = lane + 64 * t;
      x[t] = (k < 240) ? (row[k] - mean) * rstd : -1e30f;
      mx = fmaxf(mx, x[t]);
    }
#pragma unroll
    for (int off = 32; off > 0; off >>= 1) mx = fmaxf(mx, __shfl_xor(mx, off));
    float e[4], sum = 0.f;
#pragma unroll
    for (int t = 0; t < 4; t++) {
      int k = lane + 64 * t;
      e[t] = (k < 240) ? expf(x[t] - mx) : 0.f;
      sum += e[t];
    }
#pragma unroll
    for (int off = 32; off > 0; off >>= 1) sum += __shfl_xor(sum, off);
    const float inv = 1.f / sum;
#pragma unroll
    for (int t = 0; t < 4; t++) {
      int k = lane + 64 * t;
      if (k < 240) row[k] = e[t] * inv;
    }
  }
}

// ============ PV: ctx[b,n,chof+h*C4+c] = sum_k P[c,k] * V[bh,n,k]
template <int C4>
__global__ __launch_bounds__(256) void k_pv(
    const float* __restrict__ p0, const bf16_t* __restrict__ v0, bf16_t* __restrict__ c0p,
    const float* __restrict__ p1, const bf16_t* __restrict__ v1, bf16_t* __restrict__ c1p,
    int chof) {
  constexpr int NF = C4 / 16;
  const float* pr = blockIdx.z ? p1 : p0;
  const bf16_t* v = blockIdx.z ? v1 : v0;
  bf16_t* ctx = blockIdx.z ? c1p : c0p;
  const int bh = blockIdx.y, b = bh >> 2, h = bh & 3;
  const int n0 = blockIdx.x * 128;
  const int tid = threadIdx.x, lane = tid & 63, wid = tid >> 6;
  const int l15 = lane & 15, q = lane >> 4;
  __shared__ bf16_t sV[128 * KS];
  __shared__ bf16_t sP[C4 * KS];
  const f32x4 fz = {0.f, 0.f, 0.f, 0.f};
  f32x4 acc[2][NF];
  for (int i = 0; i < 2; i++) for (int f = 0; f < NF; f++) acc[i][f] = fz;
  const bf16_t* vrow = v + ((size_t)bh * N_ + n0) * 240;
  const float* pb = pr + (size_t)bh * C4 * 240;
  for (int k0 = 0; k0 < 256; k0 += 32) {
    __syncthreads();
    for (int idx = tid; idx < 512; idx += 256) {  // V uint4
      int r = idx >> 2, g = idx & 3, k = k0 + g * 8;
      if (k < 240) *(uint4*)&sV[r * KS + g * 8] = *(const uint4*)(vrow + (size_t)r * 240 + k);
      else *(uint4*)&sV[r * KS + g * 8] = make_uint4(0u, 0u, 0u, 0u);
    }
    for (int idx = tid; idx < C4 * 8; idx += 256) {  // P fp32 -> bf16 packed
      int cc = idx >> 3, cg = idx & 7, k = k0 + cg * 4;
      if (k < 240) stpk4(&sP[cc * KS + cg * 4], *(const float4*)(pb + (size_t)cc * 240 + k));
      else stz8(&sP[cc * KS + cg * 4]);
    }
    __syncthreads();
    const bf16_t* ap = &sV[(wid * 32 + l15) * KS + q * 8];
    bf16x8 a0 = *(const bf16x8*)ap;
    bf16x8 a1 = *(const bf16x8*)(ap + 16 * KS);
    for (int f = 0; f < NF; f++) {
      bf16x8 bb = *(const bf16x8*)&sP[(16 * f + l15) * KS + q * 8];
      acc[0][f] = mfma_bf16(a0, bb, acc[0][f]);
      acc[1][f] = mfma_bf16(a1, bb, acc[1][f]);
    }
  }
  bf16_t* crow = ctx + ((size_t)b * N_ + n0) * 960 + chof + h * C4;
  for (int i = 0; i < 2; i++)
    for (int f = 0; f < NF; f++)
      for (int r = 0; r < 4; r++) {
        int mm = wid * 32 + 16 * i + q * 4 + r;
        crow[(size_t)mm * 960 + 16 * f + l15] = (bf16_t)acc[i][f][r];
      }
}

// ============ out[b,n,obase+d] = sum_c ctx[b,n,chof+c] * Wob[d,c]   (fp32 out)
template <int CS>
__global__ __launch_bounds__(256) void k_wout(
    const bf16_t* __restrict__ c0p, const bf16_t* __restrict__ w0, int ob0,
    const bf16_t* __restrict__ c1p, const bf16_t* __restrict__ w1, int ob1,
    float* __restrict__ out, int chof) {
  constexpr int DT = (CS < 128) ? CS : 128;
  constexpr int NF = DT / 16;
  constexpr int DB = CS / DT;
  const int mod = blockIdx.z / DB, dch = blockIdx.z % DB;
  const bf16_t* ctx = mod ? c1p : c0p;
  const bf16_t* w = mod ? w1 : w0;
  const int obase = (mod ? ob1 : ob0) + dch * DT;
  const int m0 = blockIdx.x * 128;
  const int b = m0 >> 12, n0 = m0 & 4095;
  const int tid = threadIdx.x, lane = tid & 63, wid = tid >> 6;
  const int l15 = lane & 15, q = lane >> 4;
  __shared__ bf16_t sA[128 * KS];
  __shared__ bf16_t sB[DT * KS];
  const f32x4 fz = {0.f, 0.f, 0.f, 0.f};
  f32x4 acc[2][NF];
  for (int i = 0; i < 2; i++) for (int f = 0; f < NF; f++) acc[i][f] = fz;
  const bf16_t* arow = ctx + ((size_t)b * N_ + n0) * 960 + chof;
  const bf16_t* wb = w + (size_t)dch * DT * CS;
  for (int k0 = 0; k0 < CS; k0 += 32) {
    __syncthreads();
    for (int idx = tid; idx < 512; idx += 256) {  // ctx uint4
      int r = idx >> 2, g = idx & 3, k = k0 + g * 8;
      *(uint4*)&sA[r * KS + g * 8] = *(const uint4*)(arow + (size_t)r * 960 + k);
    }
    for (int idx = tid; idx < DT * 4; idx += 256) {  // W uint4 (bf16 pre-converted)
      int dd = idx >> 2, g = idx & 3, k = k0 + g * 8;
      *(uint4*)&sB[dd * KS + g * 8] = *(const uint4*)(wb + (size_t)dd * CS + k);
    }
    __syncthreads();
    const bf16_t* ap = &sA[(wid * 32 + l15) * KS + q * 8];
    bf16x8 a0 = *(const bf16x8*)ap;
    bf16x8 a1 = *(const bf16x8*)(ap + 16 * KS);
    for (int f = 0; f < NF; f++) {
      bf16x8 bb = *(const bf16x8*)&sB[(16 * f + l15) * KS + q * 8];
      acc[0][f] = mfma_bf16(a0, bb, acc[0][f]);
      acc[1][f] = mfma_bf16(a1, bb, acc[1][f]);
    }
  }
  float* orow = out + ((size_t)b * N_ + n0) * 1920 + obase;
  for (int i = 0; i < 2; i++)
    for (int f = 0; f < NF; f++)
      for (int r = 0; r < 4; r++) {
        int mm = wid * 32 + 16 * i + q * 4 + r;
        orow[(size_t)mm * 1920 + 16 * f + l15] = acc[i][f][r];
      }
}

extern "C" void kernel_launch(void* const* d_in, const int* in_sizes, int n_in,
                              void* d_out, int out_size, void* d_ws, size_t ws_size,
                              hipStream_t stream) {
  (void)in_sizes; (void)n_in; (void)out_size; (void)ws_size;
  const float* emb[2][4];
  const float* wq[2][4];
  const float* wo[2][4];
  for (int s = 0; s < 4; s++) {
    emb[0][s] = (const float*)d_in[2 * s];
    emb[1][s] = (const float*)d_in[2 * s + 1];
    wq[0][s] = (const float*)d_in[10 + 4 * s];
    wq[1][s] = (const float*)d_in[11 + 4 * s];
    wo[0][s] = (const float*)d_in[12 + 4 * s];
    wo[1][s] = (const float*)d_in[13 + 4 * s];
  }
  const float* emb_all = (const float*)d_in[8];
  const float* emb_alld = (const float*)d_in[9];
  const float* wkp = (const float*)d_in[26];
  const float* wvp = (const float*)d_in[27];
  const float* wkdp = (const float*)d_in[28];
  const float* wvdp = (const float*)d_in[29];
  float* out = (float*)d_out;

  // ws layout: [Kt0 Kt1 V0 V1 Q0/ctx0 Q1/ctx1 : bf16, 6*KV1] [probs fp32 2*PB1] [Wkvb][Wob]
  // Q region additionally hosts G (kvsplit bf16) before proj_q runs.
  bf16_t* w16 = (bf16_t*)d_ws;
  const size_t KV1 = (size_t)B_ * H_ * N_ * 240;  // 15,728,640
  const size_t PB1 = (size_t)B_ * H_ * 240 * 240;
  bf16_t* Kt0 = w16;
  bf16_t* Kt1 = w16 + KV1;
  bf16_t* V0 = w16 + 2 * KV1;
  bf16_t* V1 = w16 + 3 * KV1;
  bf16_t* Qb = w16 + 4 * KV1;              // G, then Qt, then ctx
  float* probs = (float*)(w16 + 6 * KV1);
  bf16_t* Wkvb = (bf16_t*)(probs + 2 * PB1);
  bf16_t* Wob = Wkvb + 230400;
  const int qcum[4] = {0, 16, 48, 112};
  const int chof[4] = {0, 64, 192, 448};
  const int soff[4] = {0, 4096, 20480, 86016};
  const dim3 blk(256);

  k_prep_w<<<dim3(256), blk, 0, stream>>>(wkp, wvp, wkdp, wvdp,
      wo[0][0], wo[0][1], wo[0][2], wo[0][3], wo[1][0], wo[1][1], wo[1][2], wo[1][3],
      Wkvb, Wob);
  hipMemsetAsync(probs, 0, 2 * PB1 * sizeof(float), stream);

  // --- kvsplit prepass: G (bf16, [mod][bh][n][240]) into the Q region ---
  k_kvsplit<<<dim3(2048), blk, 0, stream>>>(emb_all, emb_alld, Qb);
  // --- K/V projections (merged K+V per modality; K transposed) ---
  k_proj_kv<<<dim3(B_ * H_ * N_ / 64, 2), blk, 0, stream>>>(
      Qb, Wkvb, Kt0, V0, Kt1, V1);
  // --- Q projections (overwrite G with Qt; G is dead after proj_kv) ---
  for (int s = 0; s < 4; s++) {
    bf16_t* q0 = Qb + (size_t)B_ * H_ * N_ * qcum[s];
    bf16_t* q1 = q0 + KV1;
    dim3 g(B_ * N_ / 128, H_, 2);
    switch (s) {
      case 0: k_proj_q<16><<<g, blk, 0, stream>>>(emb[0][s], wq[0][s], q0, emb[1][s], wq[1][s], q1); break;
      case 1: k_proj_q<32><<<g, blk, 0, stream>>>(emb[0][s], wq[0][s], q0, emb[1][s], wq[1][s], q1); break;
      case 2: k_proj_q<64><<<g, blk, 0, stream>>>(emb[0][s], wq[0][s], q0, emb[1][s], wq[1][s], q1); break;
      case 3: k_proj_q<128><<<g, blk, 0, stream>>>(emb[0][s], wq[0][s], q0, emb[1][s], wq[1][s], q1); break;
    }
  }
  // --- scores: optical Q (mod0) x Kd^T (Kt1); DSM Q (mod1) x K^T (Kt0) ---
  for (int s = 0; s < 4; s++) {
    const bf16_t* q0 = Qb + (size_t)B_ * H_ * N_ * qcum[s];
    const bf16_t* q1 = q0 + KV1;
    float* p0 = probs + (size_t)B_ * H_ * qcum[s] * 240;
    float* p1 = p0 + PB1;
    const int c4 = 16 << s;
    dim3 g(c4 / 16, B_ * H_, 16);
    switch (s) {
      case 0: k_scores<16><<<g, blk, 0, stream>>>(q0, Kt1, p0, q1, Kt0, p1); break;
      case 1: k_scores<32><<<g, blk, 0, stream>>>(q0, Kt1, p0, q1, Kt0, p1); break;
      case 2: k_scores<64><<<g, blk, 0, stream>>>(q0, Kt1, p0, q1, Kt0, p1); break;
      case 3: k_scores<128><<<g, blk, 0, stream>>>(q0, Kt1, p0, q1, Kt0, p1); break;
    }
  }
  // --- InstanceNorm + softmax ---
  for (int s = 0; s < 4; s++) {
    float* p0 = probs + (size_t)B_ * H_ * qcum[s] * 240;
    float* p1 = p0 + PB1;
    k_inorm_softmax<<<dim3(B_ * H_, 1, 2), blk, 0, stream>>>(p0, p1, 16 << s);
  }
  // --- PV (optical uses Vd=V1, DSM uses V0); ctx overlays Q region ---
  for (int s = 0; s < 4; s++) {
    float* p0 = probs + (size_t)B_ * H_ * qcum[s] * 240;
    float* p1 = p0 + PB1;
    bf16_t* cx0 = Qb;
    bf16_t* cx1 = Qb + KV1;
    dim3 g(N_ / 128, B_ * H_, 2);
    switch (s) {
      case 0: k_pv<16><<<g, blk, 0, stream>>>(p0, V1, cx0, p1, V0, cx1, chof[s]); break;
      case 1: k_pv<32><<<g, blk, 0, stream>>>(p0, V1, cx0, p1, V0, cx1, chof[s]); break;
      case 2: k_pv<64><<<g, blk, 0, stream>>>(p0, V1, cx0, p1, V0, cx1, chof[s]); break;
      case 3: k_pv<128><<<g, blk, 0, stream>>>(p0, V1, cx0, p1, V0, cx1, chof[s]); break;
    }
  }
  // --- output projection (bf16 weights) ---
  for (int s = 0; s < 4; s++) {
    const bf16_t* cx0 = Qb;
    const bf16_t* cx1 = Qb + KV1;
    const bf16_t* w0 = Wob + soff[s];
    const bf16_t* w1 = Wob + 348160 + soff[s];
    const int cs = 64 << s;
    const int db = (cs < 128) ? 1 : cs / 128;
    dim3 g(B_ * N_ / 128, 1, 2 * db);
    switch (s) {
      case 0: k_wout<64><<<g, blk, 0, stream>>>(cx0, w0, chof[s], cx1, w1, 960 + chof[s], out, chof[s]); break;
      case 1: k_wout<128><<<g, blk, 0, stream>>>(cx0, w0, chof[s], cx1, w1, 960 + chof[s], out, chof[s]); break;
      case 2: k_wout<256><<<g, blk, 0, stream>>>(cx0, w0, chof[s], cx1, w1, 960 + chof[s], out, chof[s]); break;
      case 3: k_wout<512><<<g, blk, 0, stream>>>(cx0, w0, chof[s], cx1, w1, 960 + chof[s], out, chof[s]); break;
    }
  }
}

// Round 3
// 1092.826 us; speedup vs baseline: 1.1467x; 1.1115x over previous
//
#include <hip/hip_runtime.h>
#include <hip/hip_bf16.h>

typedef __bf16 bf16_t;
typedef __bf16 bf16x8 __attribute__((ext_vector_type(8)));
typedef float f32x4 __attribute__((ext_vector_type(4)));

static constexpr int B_ = 4, N_ = 4096, H_ = 4;
static constexpr int KS = 40;  // LDS k-stride (bf16): 80 B rows, 16B-aligned b128, 2-way max on reads

__device__ __forceinline__ f32x4 mfma_bf16(bf16x8 a, bf16x8 b, f32x4 c) {
  return __builtin_amdgcn_mfma_f32_16x16x32_bf16(a, b, c, 0, 0, 0);
}

// convert float4 -> 4 bf16 in registers, single 8 B LDS store (no scalar ds_write_b16)
__device__ __forceinline__ void stpk4(bf16_t* d, float4 v) {
  bf16_t t[4] = {(bf16_t)v.x, (bf16_t)v.y, (bf16_t)v.z, (bf16_t)v.w};
  *(uint2*)d = *(const uint2*)t;
}
__device__ __forceinline__ void stz8(bf16_t* d) { *(uint2*)d = make_uint2(0u, 0u); }

// kvsplit gather: quarter h, local col c (0..239) -> emb_all column
__device__ __forceinline__ int kvg(int h, int c) {
  if (c < 16)  return h * 16 + c;
  if (c < 48)  return 64 + h * 32 + c - 16;
  if (c < 112) return 192 + h * 64 + c - 48;
  return 448 + h * 128 + c - 112;
}

// ============ weight pre-convert fp32 -> bf16 (one pass, ~230k f4 items)
__global__ __launch_bounds__(256) void k_prep_w(
    const float* __restrict__ wk, const float* __restrict__ wv,
    const float* __restrict__ wkd, const float* __restrict__ wvd,
    const float* __restrict__ wo00, const float* __restrict__ wo01,
    const float* __restrict__ wo02, const float* __restrict__ wo03,
    const float* __restrict__ wo10, const float* __restrict__ wo11,
    const float* __restrict__ wo12, const float* __restrict__ wo13,
    bf16_t* __restrict__ Wkvb, bf16_t* __restrict__ Wob) {
  const float* wkv[4] = {wk, wv, wkd, wvd};
  const float* wo[2][4] = {{wo00, wo01, wo02, wo03}, {wo10, wo11, wo12, wo13}};
  const int soff_f4[5] = {0, 1024, 5120, 21504, 87040};
  for (int i = blockIdx.x * 256 + threadIdx.x; i < 231680; i += gridDim.x * 256) {
    if (i < 57600) {  // kv weights: 4 x 14400 f4
      int t = i / 14400, r = i - t * 14400;
      float4 v = *(const float4*)(wkv[t] + r * 4);
      stpk4(Wkvb + (size_t)t * 57600 + r * 4, v);
    } else {  // wout: 2 x 87040 f4
      int j = i - 57600;
      int mod = j / 87040, jr = j - mod * 87040;
      int s = (jr < 1024) ? 0 : (jr < 5120) ? 1 : (jr < 21504) ? 2 : 3;
      float4 v = *(const float4*)(wo[mod][s] + (jr - soff_f4[s]) * 4);
      stpk4(Wob + (size_t)mod * 348160 + jr * 4, v);
    }
  }
}

// ============ kvsplit prepass: emb_all fp32 [b,n,960] -> G bf16 [mod][bh][n][240]
// one 16B output chunk per item (8 cols; segments are multiples of 8 so no chunk crosses one)
__global__ __launch_bounds__(256) void k_kvsplit(
    const float* __restrict__ eA, const float* __restrict__ eB,
    bf16_t* __restrict__ G) {
  const int TOT = 2 * 16 * 4096 * 30;  // 3,932,160 chunks
  for (int i = blockIdx.x * 256 + threadIdx.x; i < TOT; i += gridDim.x * 256) {
    int t = i / 30;                 // row index: mod*65536 + bh*4096 + n
    int cg = i - t * 30;
    int mod = t >> 16;
    int row = t & 65535;            // bh*4096 + n
    int bh = row >> 12, n = row & 4095;
    int b = bh >> 2, h = bh & 3;
    int col = kvg(h, cg * 8);
    const float* src = (mod ? eB : eA) + ((size_t)b * N_ + n) * 960 + col;
    float4 v0 = *(const float4*)src;
    float4 v1 = *(const float4*)(src + 4);
    bf16_t o[8] = {(bf16_t)v0.x, (bf16_t)v0.y, (bf16_t)v0.z, (bf16_t)v0.w,
                   (bf16_t)v1.x, (bf16_t)v1.y, (bf16_t)v1.z, (bf16_t)v1.w};
    *(uint4*)(G + (size_t)t * 240 + cg * 8) = *(const uint4*)o;
  }
}

// ============ Q projection: Q[bh,n,d] -> written TRANSPOSED Qt[bh][d][4096] (packed uint2)
template <int C4>
__global__ __launch_bounds__(256) void k_proj_q(
    const float* __restrict__ e0, const float* __restrict__ w0, bf16_t* __restrict__ o0,
    const float* __restrict__ e1, const float* __restrict__ w1, bf16_t* __restrict__ o1) {
  constexpr int KP = (C4 < 32) ? 32 : C4;
  constexpr int NF = C4 / 16;
  const float* emb = blockIdx.z ? e1 : e0;
  const float* wq = blockIdx.z ? w1 : w0;
  bf16_t* qout = blockIdx.z ? o1 : o0;
  const int h = blockIdx.y;
  const int m0 = blockIdx.x * 128;
  const int b = m0 >> 12, n0 = m0 & 4095;
  const int tid = threadIdx.x, lane = tid & 63, wid = tid >> 6;
  const int l15 = lane & 15, q = lane >> 4;
  __shared__ bf16_t sA[128 * KS];
  __shared__ bf16_t sB[C4 * KS];
  const f32x4 fz = {0.f, 0.f, 0.f, 0.f};
  f32x4 acc[2][NF];
  for (int i = 0; i < 2; i++) for (int f = 0; f < NF; f++) acc[i][f] = fz;
  const float* srow = emb + ((size_t)b * N_ + n0) * (H_ * C4) + h * C4;
  const float* wb = wq + h * C4 * C4;
  for (int k0 = 0; k0 < KP; k0 += 32) {
    __syncthreads();
    for (int idx = tid; idx < 1024; idx += 256) {
      int r = idx >> 3, cg = idx & 7, c = k0 + cg * 4;
      if (c < C4) stpk4(&sA[r * KS + cg * 4], *(const float4*)(srow + (size_t)r * (H_ * C4) + c));
      else stz8(&sA[r * KS + cg * 4]);
    }
    for (int idx = tid; idx < C4 * 8; idx += 256) {
      int dd = idx >> 3, cg = idx & 7, c = k0 + cg * 4;
      if (c < C4) stpk4(&sB[dd * KS + cg * 4], *(const float4*)(wb + dd * C4 + c));
      else stz8(&sB[dd * KS + cg * 4]);
    }
    __syncthreads();
    const bf16_t* ap = &sA[(wid * 32 + l15) * KS + q * 8];
    bf16x8 a0 = *(const bf16x8*)ap;
    bf16x8 a1 = *(const bf16x8*)(ap + 16 * KS);
    for (int f = 0; f < NF; f++) {
      bf16x8 bb = *(const bf16x8*)&sB[(16 * f + l15) * KS + q * 8];
      acc[0][f] = mfma_bf16(a0, bb, acc[0][f]);
      acc[1][f] = mfma_bf16(a1, bb, acc[1][f]);
    }
  }
  // transposed write: Qt row c = 16f+l15, cols n = n0 + wid*32 + 16i + q*4 + r (4 packed)
  bf16_t* qbh = qout + (size_t)(b * H_ + h) * C4 * 4096;
  for (int i = 0; i < 2; i++)
    for (int f = 0; f < NF; f++) {
      bf16_t pk[4];
      for (int r = 0; r < 4; r++) pk[r] = (bf16_t)acc[i][f][r];
      *(uint2*)(qbh + (size_t)(16 * f + l15) * 4096 + n0 + wid * 32 + 16 * i + q * 4) =
          *(const uint2*)pk;
    }
}

// ============ K/V projection, merged per modality; 512 threads, 128 rows/block.
// T14 split staging: issue global loads for step t+1 before MFMA(t); ds_write after barrier.
// A from pre-converted G (bf16, coalesced uint4). K stored transposed [bh][240][4096]; V n-major.
__global__ __launch_bounds__(512) void k_proj_kv(
    const bf16_t* __restrict__ G, const bf16_t* __restrict__ Wkvb,
    bf16_t* __restrict__ Kt0, bf16_t* __restrict__ V0,
    bf16_t* __restrict__ Kt1, bf16_t* __restrict__ V1) {
  const int mod = blockIdx.y;
  const bf16_t* src = G + (size_t)mod * ((size_t)B_ * H_ * N_ * 240);
  const bf16_t* wK = Wkvb + (size_t)(2 * mod) * 57600;
  const bf16_t* wV = Wkvb + (size_t)(2 * mod + 1) * 57600;
  bf16_t* Kt = mod ? Kt1 : Kt0;
  bf16_t* V = mod ? V1 : V0;
  const int m0 = blockIdx.x * 128;
  const int bh = m0 >> 12, n0 = m0 & 4095;
  const int tid = threadIdx.x, lane = tid & 63, wid = tid >> 6;  // wid 0..7
  const int l15 = lane & 15, q = lane >> 4;
  __shared__ bf16_t sA[128 * KS];
  __shared__ bf16_t sB[2][240 * KS];
  const f32x4 fz = {0.f, 0.f, 0.f, 0.f};
  f32x4 accK[15], accV[15];
  for (int f = 0; f < 15; f++) { accK[f] = fz; accV[f] = fz; }
  const bf16_t* arow = src + (size_t)m0 * 240;
  const uint4 z4 = make_uint4(0u, 0u, 0u, 0u);

  // staging registers: A 1 uint4/thread (128 rows x 4 groups), B 1920 items over 512 threads
  const int ar = tid >> 2, ag = tid & 3;          // A row / col-group
  int bm[4], bd[4], bg[4];                        // B tile (K/V), row, col-group
#pragma unroll
  for (int j = 0; j < 4; j++) {
    int idx = tid + 512 * j;
    bm[j] = idx >= 960;
    int jj = idx - (bm[j] ? 960 : 0);
    bd[j] = jj >> 2; bg[j] = jj & 3;
  }
  uint4 ra, rb0, rb1, rb2, rb3;

#define KV_LOAD(K0)                                                                    \
  {                                                                                    \
    int c = (K0) + ag * 8;                                                             \
    ra = (c < 240) ? *(const uint4*)(arow + (size_t)ar * 240 + c) : z4;                \
    int c0_ = (K0) + bg[0] * 8;                                                        \
    rb0 = (c0_ < 240) ? *(const uint4*)((bm[0] ? wV : wK) + bd[0] * 240 + c0_) : z4;   \
    int c1_ = (K0) + bg[1] * 8;                                                        \
    rb1 = (c1_ < 240) ? *(const uint4*)((bm[1] ? wV : wK) + bd[1] * 240 + c1_) : z4;   \
    int c2_ = (K0) + bg[2] * 8;                                                        \
    rb2 = (c2_ < 240) ? *(const uint4*)((bm[2] ? wV : wK) + bd[2] * 240 + c2_) : z4;   \
    if (tid < 384) {                                                                   \
      int c3_ = (K0) + bg[3] * 8;                                                      \
      rb3 = (c3_ < 240) ? *(const uint4*)((bm[3] ? wV : wK) + bd[3] * 240 + c3_) : z4; \
    }                                                                                  \
  }
#define KV_WRITE()                                                                     \
  {                                                                                    \
    *(uint4*)&sA[ar * KS + ag * 8] = ra;                                               \
    *(uint4*)&sB[bm[0]][bd[0] * KS + bg[0] * 8] = rb0;                                 \
    *(uint4*)&sB[bm[1]][bd[1] * KS + bg[1] * 8] = rb1;                                 \
    *(uint4*)&sB[bm[2]][bd[2] * KS + bg[2] * 8] = rb2;                                 \
    if (tid < 384) *(uint4*)&sB[bm[3]][bd[3] * KS + bg[3] * 8] = rb3;                  \
  }

  KV_LOAD(0);
  KV_WRITE();
  for (int t = 0; t < 8; t++) {
    if (t < 7) KV_LOAD((t + 1) * 32);  // issue next-step loads; latency hides under MFMA
    __syncthreads();                   // staged writes visible
    bf16x8 a = *(const bf16x8*)&sA[(wid * 16 + l15) * KS + q * 8];
#pragma unroll
    for (int f = 0; f < 15; f++) {
      bf16x8 bk = *(const bf16x8*)&sB[0][(16 * f + l15) * KS + q * 8];
      bf16x8 bv = *(const bf16x8*)&sB[1][(16 * f + l15) * KS + q * 8];
      accK[f] = mfma_bf16(a, bk, accK[f]);
      accV[f] = mfma_bf16(a, bv, accV[f]);
    }
    __syncthreads();                   // all reads done before overwrite
    if (t < 7) KV_WRITE();             // vmcnt drain + ds_write (post-MFMA)
  }
#undef KV_LOAD
#undef KV_WRITE

  // K^T: rows k=16f+l15, cols n (4 consecutive packed in b64)
  for (int f = 0; f < 15; f++) {
    bf16_t pk[4];
    for (int r = 0; r < 4; r++) pk[r] = (bf16_t)accK[f][r];
    bf16_t* dst = Kt + ((size_t)bh * 240 + 16 * f + l15) * 4096 + n0 + wid * 16 + q * 4;
    *(uint2*)dst = *(const uint2*)pk;
  }
  // V n-major
  bf16_t* orow = V + ((size_t)bh * N_ + n0) * 240;
  for (int f = 0; f < 15; f++)
    for (int r = 0; r < 4; r++) {
      int mm = wid * 16 + q * 4 + r;
      orow[(size_t)mm * 240 + 16 * f + l15] = (bf16_t)accV[f][r];
    }
}

// ============ scores: S[c,k] += (1/sqrt960) sum_{n chunk} Qt[c,n]*K^T[k,n]
// both operands staged via contiguous uint4 (Q now stored transposed)
template <int C4>
__global__ __launch_bounds__(256) void k_scores(
    const bf16_t* __restrict__ q0, const bf16_t* __restrict__ kt0, float* __restrict__ s0,
    const bf16_t* __restrict__ q1, const bf16_t* __restrict__ kt1, float* __restrict__ s1) {
  const int mod = blockIdx.z >> 3, chunk = blockIdx.z & 7;
  const bf16_t* qp = mod ? q1 : q0;
  const bf16_t* ktp = mod ? kt1 : kt0;
  float* sc = mod ? s1 : s0;
  const int bh = blockIdx.y;
  const int c0 = blockIdx.x * 16;
  const int tid = threadIdx.x, lane = tid & 63, wid = tid >> 6;
  const int l15 = lane & 15, q = lane >> 4;
  __shared__ bf16_t sQ[16 * KS];
  __shared__ bf16_t sK[240 * KS];
  const f32x4 fz = {0.f, 0.f, 0.f, 0.f};
  f32x4 acc[4] = {fz, fz, fz, fz};
  const bf16_t* ktb = ktp + (size_t)bh * 240 * 4096 + chunk * 512;
  const bf16_t* qb = qp + ((size_t)bh * C4 + c0) * 4096 + chunk * 512;
  for (int k0 = 0; k0 < 512; k0 += 32) {
    __syncthreads();
    if (tid < 64) {  // Q^T contiguous uint4 (16 c-rows x 32 n)
      int ci = tid >> 2, g = tid & 3;
      *(uint4*)&sQ[ci * KS + g * 8] = *(const uint4*)(qb + (size_t)ci * 4096 + k0 + g * 8);
    }
    for (int idx = tid; idx < 960; idx += 256) {  // K^T contiguous uint4
      int kk = idx >> 2, g = idx & 3;
      *(uint4*)&sK[kk * KS + g * 8] = *(const uint4*)(ktb + (size_t)kk * 4096 + k0 + g * 8);
    }
    __syncthreads();
    bf16x8 af = *(const bf16x8*)&sQ[l15 * KS + q * 8];
    for (int j = 0; j < 4; j++) {
      int f = wid + 4 * j;
      if (f < 15) {
        bf16x8 bb = *(const bf16x8*)&sK[(16 * f + l15) * KS + q * 8];
        acc[j] = mfma_bf16(af, bb, acc[j]);
      }
    }
  }
  const float rs = 0.0322748612183951f;  // 1/sqrt(960)
  float* sb = sc + (size_t)bh * C4 * 240;
  for (int j = 0; j < 4; j++) {
    int f = wid + 4 * j;
    if (f < 15)
      for (int r = 0; r < 4; r++)
        atomicAdd(&sb[(size_t)(c0 + q * 4 + r) * 240 + 16 * f + l15], acc[j][r] * rs);
  }
}

// ============ InstanceNorm over (c,k) per (b,h), then softmax over k (240)
__global__ __launch_bounds__(256) void k_inorm_softmax(float* __restrict__ p0,
                                                       float* __restrict__ p1, int c4) {
  float* p = (blockIdx.z ? p1 : p0) + (size_t)blockIdx.x * c4 * 240;
  const int tid = threadIdx.x;
  const int tot = c4 * 240;
  float s = 0.f, s2 = 0.f;
  for (int idx = tid; idx < tot; idx += 256) {
    float v = p[idx];
    s += v; s2 += v * v;
  }
#pragma unroll
  for (int off = 32; off > 0; off >>= 1) {
    s += __shfl_xor(s, off);
    s2 += __shfl_xor(s2, off);
  }
  __shared__ float rsum[4], rsum2[4], smv[2];
  const int wid = tid >> 6, lane = tid & 63;
  if (lane == 0) { rsum[wid] = s; rsum2[wid] = s2; }
  __syncthreads();
  if (tid == 0) {
    float ts = rsum[0] + rsum[1] + rsum[2] + rsum[3];
    float ts2 = rsum2[0] + rsum2[1] + rsum2[2] + rsum2[3];
    float mean = ts / tot;
    float var = ts2 / tot - mean * mean;
    smv[0] = mean; smv[1] = rsqrtf(var + 1e-5f);
  }
  __syncthreads();
  const float mean = smv[0], rstd = smv[1];
  for (int c = wid; c < c4; c += 4) {
    float* row = p + (size_t)c * 240;
    float x[4]; float mx = -1e30f;
#pragma unroll
    for (int t = 0; t < 4; t++) {
      int k = lane + 64 * t;
      x[t] = (k < 240) ? (row[k] - mean) * rstd : -1e30f;
      mx = fmaxf(mx, x[t]);
    }
#pragma unroll
    for (int off = 32; off > 0; off >>= 1) mx = fmaxf(mx, __shfl_xor(mx, off));
    float e[4], sum = 0.f;
#pragma unroll
    for (int t = 0; t < 4; t++) {
      int k = lane + 64 * t;
      e[t] = (k < 240) ? expf(x[t] - mx) : 0.f;
      sum += e[t];
    }
#pragma unroll
    for (int off = 32; off > 0; off >>= 1) sum += __shfl_xor(sum, off);
    const float inv = 1.f / sum;
#pragma unroll
    for (int t = 0; t < 4; t++) {
      int k = lane + 64 * t;
      if (k < 240) row[k] = e[t] * inv;
    }
  }
}

// ============ PV: ctx[b,n,chof+h*C4+c] = sum_k P[c,k] * V[bh,n,k]
template <int C4>
__global__ __launch_bounds__(256) void k_pv(
    const float* __restrict__ p0, const bf16_t* __restrict__ v0, bf16_t* __restrict__ c0p,
    const float* __restrict__ p1, const bf16_t* __restrict__ v1, bf16_t* __restrict__ c1p,
    int chof) {
  constexpr int NF = C4 / 16;
  const float* pr = blockIdx.z ? p1 : p0;
  const bf16_t* v = blockIdx.z ? v1 : v0;
  bf16_t* ctx = blockIdx.z ? c1p : c0p;
  const int bh = blockIdx.y, b = bh >> 2, h = bh & 3;
  const int n0 = blockIdx.x * 128;
  const int tid = threadIdx.x, lane = tid & 63, wid = tid >> 6;
  const int l15 = lane & 15, q = lane >> 4;
  __shared__ bf16_t sV[128 * KS];
  __shared__ bf16_t sP[C4 * KS];
  const f32x4 fz = {0.f, 0.f, 0.f, 0.f};
  f32x4 acc[2][NF];
  for (int i = 0; i < 2; i++) for (int f = 0; f < NF; f++) acc[i][f] = fz;
  const bf16_t* vrow = v + ((size_t)bh * N_ + n0) * 240;
  const float* pb = pr + (size_t)bh * C4 * 240;
  for (int k0 = 0; k0 < 256; k0 += 32) {
    __syncthreads();
    for (int idx = tid; idx < 512; idx += 256) {  // V uint4
      int r = idx >> 2, g = idx & 3, k = k0 + g * 8;
      if (k < 240) *(uint4*)&sV[r * KS + g * 8] = *(const uint4*)(vrow + (size_t)r * 240 + k);
      else *(uint4*)&sV[r * KS + g * 8] = make_uint4(0u, 0u, 0u, 0u);
    }
    for (int idx = tid; idx < C4 * 8; idx += 256) {  // P fp32 -> bf16 packed
      int cc = idx >> 3, cg = idx & 7, k = k0 + cg * 4;
      if (k < 240) stpk4(&sP[cc * KS + cg * 4], *(const float4*)(pb + (size_t)cc * 240 + k));
      else stz8(&sP[cc * KS + cg * 4]);
    }
    __syncthreads();
    const bf16_t* ap = &sV[(wid * 32 + l15) * KS + q * 8];
    bf16x8 a0 = *(const bf16x8*)ap;
    bf16x8 a1 = *(const bf16x8*)(ap + 16 * KS);
    for (int f = 0; f < NF; f++) {
      bf16x8 bb = *(const bf16x8*)&sP[(16 * f + l15) * KS + q * 8];
      acc[0][f] = mfma_bf16(a0, bb, acc[0][f]);
      acc[1][f] = mfma_bf16(a1, bb, acc[1][f]);
    }
  }
  bf16_t* crow = ctx + ((size_t)b * N_ + n0) * 960 + chof + h * C4;
  for (int i = 0; i < 2; i++)
    for (int f = 0; f < NF; f++)
      for (int r = 0; r < 4; r++) {
        int mm = wid * 32 + 16 * i + q * 4 + r;
        crow[(size_t)mm * 960 + 16 * f + l15] = (bf16_t)acc[i][f][r];
      }
}

// ============ out[b,n,obase+d] = sum_c ctx[b,n,chof+c] * Wob[d,c]   (fp32 out)
template <int CS>
__global__ __launch_bounds__(256) void k_wout(
    const bf16_t* __restrict__ c0p, const bf16_t* __restrict__ w0, int ob0,
    const bf16_t* __restrict__ c1p, const bf16_t* __restrict__ w1, int ob1,
    float* __restrict__ out, int chof) {
  constexpr int DT = (CS < 128) ? CS : 128;
  constexpr int NF = DT / 16;
  constexpr int DB = CS / DT;
  const int mod = blockIdx.z / DB, dch = blockIdx.z % DB;
  const bf16_t* ctx = mod ? c1p : c0p;
  const bf16_t* w = mod ? w1 : w0;
  const int obase = (mod ? ob1 : ob0) + dch * DT;
  const int m0 = blockIdx.x * 128;
  const int b = m0 >> 12, n0 = m0 & 4095;
  const int tid = threadIdx.x, lane = tid & 63, wid = tid >> 6;
  const int l15 = lane & 15, q = lane >> 4;
  __shared__ bf16_t sA[128 * KS];
  __shared__ bf16_t sB[DT * KS];
  const f32x4 fz = {0.f, 0.f, 0.f, 0.f};
  f32x4 acc[2][NF];
  for (int i = 0; i < 2; i++) for (int f = 0; f < NF; f++) acc[i][f] = fz;
  const bf16_t* arow = ctx + ((size_t)b * N_ + n0) * 960 + chof;
  const bf16_t* wb = w + (size_t)dch * DT * CS;
  for (int k0 = 0; k0 < CS; k0 += 32) {
    __syncthreads();
    for (int idx = tid; idx < 512; idx += 256) {  // ctx uint4
      int r = idx >> 2, g = idx & 3, k = k0 + g * 8;
      *(uint4*)&sA[r * KS + g * 8] = *(const uint4*)(arow + (size_t)r * 960 + k);
    }
    for (int idx = tid; idx < DT * 4; idx += 256) {  // W uint4 (bf16 pre-converted)
      int dd = idx >> 2, g = idx & 3, k = k0 + g * 8;
      *(uint4*)&sB[dd * KS + g * 8] = *(const uint4*)(wb + (size_t)dd * CS + k);
    }
    __syncthreads();
    const bf16_t* ap = &sA[(wid * 32 + l15) * KS + q * 8];
    bf16x8 a0 = *(const bf16x8*)ap;
    bf16x8 a1 = *(const bf16x8*)(ap + 16 * KS);
    for (int f = 0; f < NF; f++) {
      bf16x8 bb = *(const bf16x8*)&sB[(16 * f + l15) * KS + q * 8];
      acc[0][f] = mfma_bf16(a0, bb, acc[0][f]);
      acc[1][f] = mfma_bf16(a1, bb, acc[1][f]);
    }
  }
  float* orow = out + ((size_t)b * N_ + n0) * 1920 + obase;
  for (int i = 0; i < 2; i++)
    for (int f = 0; f < NF; f++)
      for (int r = 0; r < 4; r++) {
        int mm = wid * 32 + 16 * i + q * 4 + r;
        orow[(size_t)mm * 1920 + 16 * f + l15] = acc[i][f][r];
      }
}

extern "C" void kernel_launch(void* const* d_in, const int* in_sizes, int n_in,
                              void* d_out, int out_size, void* d_ws, size_t ws_size,
                              hipStream_t stream) {
  (void)in_sizes; (void)n_in; (void)out_size; (void)ws_size;
  const float* emb[2][4];
  const float* wq[2][4];
  const float* wo[2][4];
  for (int s = 0; s < 4; s++) {
    emb[0][s] = (const float*)d_in[2 * s];
    emb[1][s] = (const float*)d_in[2 * s + 1];
    wq[0][s] = (const float*)d_in[10 + 4 * s];
    wq[1][s] = (const float*)d_in[11 + 4 * s];
    wo[0][s] = (const float*)d_in[12 + 4 * s];
    wo[1][s] = (const float*)d_in[13 + 4 * s];
  }
  const float* emb_all = (const float*)d_in[8];
  const float* emb_alld = (const float*)d_in[9];
  const float* wkp = (const float*)d_in[26];
  const float* wvp = (const float*)d_in[27];
  const float* wkdp = (const float*)d_in[28];
  const float* wvdp = (const float*)d_in[29];
  float* out = (float*)d_out;

  // ws layout: [Kt0 Kt1 V0 V1 Q0/ctx0 Q1/ctx1 : bf16, 6*KV1] [probs fp32 2*PB1] [Wkvb][Wob]
  // Q region additionally hosts G (kvsplit bf16) before proj_q runs.
  bf16_t* w16 = (bf16_t*)d_ws;
  const size_t KV1 = (size_t)B_ * H_ * N_ * 240;  // 15,728,640
  const size_t PB1 = (size_t)B_ * H_ * 240 * 240;
  bf16_t* Kt0 = w16;
  bf16_t* Kt1 = w16 + KV1;
  bf16_t* V0 = w16 + 2 * KV1;
  bf16_t* V1 = w16 + 3 * KV1;
  bf16_t* Qb = w16 + 4 * KV1;              // G, then Qt, then ctx
  float* probs = (float*)(w16 + 6 * KV1);
  bf16_t* Wkvb = (bf16_t*)(probs + 2 * PB1);
  bf16_t* Wob = Wkvb + 230400;
  const int qcum[4] = {0, 16, 48, 112};
  const int chof[4] = {0, 64, 192, 448};
  const int soff[4] = {0, 4096, 20480, 86016};
  const dim3 blk(256);

  k_prep_w<<<dim3(256), blk, 0, stream>>>(wkp, wvp, wkdp, wvdp,
      wo[0][0], wo[0][1], wo[0][2], wo[0][3], wo[1][0], wo[1][1], wo[1][2], wo[1][3],
      Wkvb, Wob);
  hipMemsetAsync(probs, 0, 2 * PB1 * sizeof(float), stream);

  // --- kvsplit prepass: G (bf16, [mod][bh][n][240]) into the Q region ---
  k_kvsplit<<<dim3(2048), blk, 0, stream>>>(emb_all, emb_alld, Qb);
  // --- K/V projections (merged K+V per modality; K transposed; 512-thread blocks) ---
  k_proj_kv<<<dim3(B_ * H_ * N_ / 128, 2), dim3(512), 0, stream>>>(
      Qb, Wkvb, Kt0, V0, Kt1, V1);
  // --- Q projections (overwrite G with Qt; G is dead after proj_kv) ---
  for (int s = 0; s < 4; s++) {
    bf16_t* q0 = Qb + (size_t)B_ * H_ * N_ * qcum[s];
    bf16_t* q1 = q0 + KV1;
    dim3 g(B_ * N_ / 128, H_, 2);
    switch (s) {
      case 0: k_proj_q<16><<<g, blk, 0, stream>>>(emb[0][s], wq[0][s], q0, emb[1][s], wq[1][s], q1); break;
      case 1: k_proj_q<32><<<g, blk, 0, stream>>>(emb[0][s], wq[0][s], q0, emb[1][s], wq[1][s], q1); break;
      case 2: k_proj_q<64><<<g, blk, 0, stream>>>(emb[0][s], wq[0][s], q0, emb[1][s], wq[1][s], q1); break;
      case 3: k_proj_q<128><<<g, blk, 0, stream>>>(emb[0][s], wq[0][s], q0, emb[1][s], wq[1][s], q1); break;
    }
  }
  // --- scores: optical Q (mod0) x Kd^T (Kt1); DSM Q (mod1) x K^T (Kt0) ---
  for (int s = 0; s < 4; s++) {
    const bf16_t* q0 = Qb + (size_t)B_ * H_ * N_ * qcum[s];
    const bf16_t* q1 = q0 + KV1;
    float* p0 = probs + (size_t)B_ * H_ * qcum[s] * 240;
    float* p1 = p0 + PB1;
    const int c4 = 16 << s;
    dim3 g(c4 / 16, B_ * H_, 16);
    switch (s) {
      case 0: k_scores<16><<<g, blk, 0, stream>>>(q0, Kt1, p0, q1, Kt0, p1); break;
      case 1: k_scores<32><<<g, blk, 0, stream>>>(q0, Kt1, p0, q1, Kt0, p1); break;
      case 2: k_scores<64><<<g, blk, 0, stream>>>(q0, Kt1, p0, q1, Kt0, p1); break;
      case 3: k_scores<128><<<g, blk, 0, stream>>>(q0, Kt1, p0, q1, Kt0, p1); break;
    }
  }
  // --- InstanceNorm + softmax ---
  for (int s = 0; s < 4; s++) {
    float* p0 = probs + (size_t)B_ * H_ * qcum[s] * 240;
    float* p1 = p0 + PB1;
    k_inorm_softmax<<<dim3(B_ * H_, 1, 2), blk, 0, stream>>>(p0, p1, 16 << s);
  }
  // --- PV (optical uses Vd=V1, DSM uses V0); ctx overlays Q region ---
  for (int s = 0; s < 4; s++) {
    float* p0 = probs + (size_t)B_ * H_ * qcum[s] * 240;
    float* p1 = p0 + PB1;
    bf16_t* cx0 = Qb;
    bf16_t* cx1 = Qb + KV1;
    dim3 g(N_ / 128, B_ * H_, 2);
    switch (s) {
      case 0: k_pv<16><<<g, blk, 0, stream>>>(p0, V1, cx0, p1, V0, cx1, chof[s]); break;
      case 1: k_pv<32><<<g, blk, 0, stream>>>(p0, V1, cx0, p1, V0, cx1, chof[s]); break;
      case 2: k_pv<64><<<g, blk, 0, stream>>>(p0, V1, cx0, p1, V0, cx1, chof[s]); break;
      case 3: k_pv<128><<<g, blk, 0, stream>>>(p0, V1, cx0, p1, V0, cx1, chof[s]); break;
    }
  }
  // --- output projection (bf16 weights) ---
  for (int s = 0; s < 4; s++) {
    const bf16_t* cx0 = Qb;
    const bf16_t* cx1 = Qb + KV1;
    const bf16_t* w0 = Wob + soff[s];
    const bf16_t* w1 = Wob + 348160 + soff[s];
    const int cs = 64 << s;
    const int db = (cs < 128) ? 1 : cs / 128;
    dim3 g(B_ * N_ / 128, 1, 2 * db);
    switch (s) {
      case 0: k_wout<64><<<g, blk, 0, stream>>>(cx0, w0, chof[s], cx1, w1, 960 + chof[s], out, chof[s]); break;
      case 1: k_wout<128><<<g, blk, 0, stream>>>(cx0, w0, chof[s], cx1, w1, 960 + chof[s], out, chof[s]); break;
      case 2: k_wout<256><<<g, blk, 0, stream>>>(cx0, w0, chof[s], cx1, w1, 960 + chof[s], out, chof[s]); break;
      case 3: k_wout<512><<<g, blk, 0, stream>>>(cx0, w0, chof[s], cx1, w1, 960 + chof[s], out, chof[s]); break;
    }
  }
}

// Round 4
// 912.088 us; speedup vs baseline: 1.3739x; 1.1982x over previous
//
#include <hip/hip_runtime.h>
#include <hip/hip_bf16.h>

typedef __bf16 bf16_t;
typedef __bf16 bf16x8 __attribute__((ext_vector_type(8)));
typedef float f32x4 __attribute__((ext_vector_type(4)));

static constexpr int B_ = 4, N_ = 4096, H_ = 4;
static constexpr int KS = 40;  // LDS k-stride (bf16): 80 B rows, 16B-aligned b128, 2-way max on reads

__device__ __forceinline__ f32x4 mfma_bf16(bf16x8 a, bf16x8 b, f32x4 c) {
  return __builtin_amdgcn_mfma_f32_16x16x32_bf16(a, b, c, 0, 0, 0);
}

// convert float4 -> 4 bf16 in registers, single 8 B LDS store (no scalar ds_write_b16)
__device__ __forceinline__ void stpk4(bf16_t* d, float4 v) {
  bf16_t t[4] = {(bf16_t)v.x, (bf16_t)v.y, (bf16_t)v.z, (bf16_t)v.w};
  *(uint2*)d = *(const uint2*)t;
}
__device__ __forceinline__ void stz8(bf16_t* d) { *(uint2*)d = make_uint2(0u, 0u); }

// kvsplit gather: quarter h, local col c (0..239) -> emb_all column
__device__ __forceinline__ int kvg(int h, int c) {
  if (c < 16)  return h * 16 + c;
  if (c < 48)  return 64 + h * 32 + c - 16;
  if (c < 112) return 192 + h * 64 + c - 48;
  return 448 + h * 128 + c - 112;
}

// global Q row r (0..239) -> scale index
__device__ __forceinline__ int qsc(int r) { return (r < 16) ? 0 : (r < 48) ? 1 : (r < 112) ? 2 : 3; }

// ============ weight pre-convert fp32 -> bf16 (one pass, ~230k f4 items)
__global__ __launch_bounds__(256) void k_prep_w(
    const float* __restrict__ wk, const float* __restrict__ wv,
    const float* __restrict__ wkd, const float* __restrict__ wvd,
    const float* __restrict__ wo00, const float* __restrict__ wo01,
    const float* __restrict__ wo02, const float* __restrict__ wo03,
    const float* __restrict__ wo10, const float* __restrict__ wo11,
    const float* __restrict__ wo12, const float* __restrict__ wo13,
    bf16_t* __restrict__ Wkvb, bf16_t* __restrict__ Wob) {
  const float* wkv[4] = {wk, wv, wkd, wvd};
  const float* wo[2][4] = {{wo00, wo01, wo02, wo03}, {wo10, wo11, wo12, wo13}};
  const int soff_f4[5] = {0, 1024, 5120, 21504, 87040};
  for (int i = blockIdx.x * 256 + threadIdx.x; i < 231680; i += gridDim.x * 256) {
    if (i < 57600) {  // kv weights: 4 x 14400 f4
      int t = i / 14400, r = i - t * 14400;
      float4 v = *(const float4*)(wkv[t] + r * 4);
      stpk4(Wkvb + (size_t)t * 57600 + r * 4, v);
    } else {  // wout: 2 x 87040 f4
      int j = i - 57600;
      int mod = j / 87040, jr = j - mod * 87040;
      int s = (jr < 1024) ? 0 : (jr < 5120) ? 1 : (jr < 21504) ? 2 : 3;
      float4 v = *(const float4*)(wo[mod][s] + (jr - soff_f4[s]) * 4);
      stpk4(Wob + (size_t)mod * 348160 + jr * 4, v);
    }
  }
}

// ============ kvsplit prepass: emb_all fp32 [b,n,960] -> G bf16 [mod][bh][n][240]
__global__ __launch_bounds__(256) void k_kvsplit(
    const float* __restrict__ eA, const float* __restrict__ eB,
    bf16_t* __restrict__ G) {
  const int TOT = 2 * 16 * 4096 * 30;  // 3,932,160 chunks
  for (int i = blockIdx.x * 256 + threadIdx.x; i < TOT; i += gridDim.x * 256) {
    int t = i / 30;                 // row index: mod*65536 + bh*4096 + n
    int cg = i - t * 30;
    int mod = t >> 16;
    int row = t & 65535;            // bh*4096 + n
    int bh = row >> 12, n = row & 4095;
    int b = bh >> 2, h = bh & 3;
    int col = kvg(h, cg * 8);
    const float* src = (mod ? eB : eA) + ((size_t)b * N_ + n) * 960 + col;
    float4 v0 = *(const float4*)src;
    float4 v1 = *(const float4*)(src + 4);
    bf16_t o[8] = {(bf16_t)v0.x, (bf16_t)v0.y, (bf16_t)v0.z, (bf16_t)v0.w,
                   (bf16_t)v1.x, (bf16_t)v1.y, (bf16_t)v1.z, (bf16_t)v1.w};
    *(uint4*)(G + (size_t)t * 240 + cg * 8) = *(const uint4*)o;
  }
}

// ============ Q projection: Q[bh,n,d] -> written TRANSPOSED Qt[bh][d][4096] (packed uint2)
template <int C4>
__global__ __launch_bounds__(256) void k_proj_q(
    const float* __restrict__ e0, const float* __restrict__ w0, bf16_t* __restrict__ o0,
    const float* __restrict__ e1, const float* __restrict__ w1, bf16_t* __restrict__ o1) {
  constexpr int KP = (C4 < 32) ? 32 : C4;
  constexpr int NF = C4 / 16;
  const float* emb = blockIdx.z ? e1 : e0;
  const float* wq = blockIdx.z ? w1 : w0;
  bf16_t* qout = blockIdx.z ? o1 : o0;
  const int h = blockIdx.y;
  const int m0 = blockIdx.x * 128;
  const int b = m0 >> 12, n0 = m0 & 4095;
  const int tid = threadIdx.x, lane = tid & 63, wid = tid >> 6;
  const int l15 = lane & 15, q = lane >> 4;
  __shared__ bf16_t sA[128 * KS];
  __shared__ bf16_t sB[C4 * KS];
  const f32x4 fz = {0.f, 0.f, 0.f, 0.f};
  f32x4 acc[2][NF];
  for (int i = 0; i < 2; i++) for (int f = 0; f < NF; f++) acc[i][f] = fz;
  const float* srow = emb + ((size_t)b * N_ + n0) * (H_ * C4) + h * C4;
  const float* wb = wq + h * C4 * C4;
  for (int k0 = 0; k0 < KP; k0 += 32) {
    __syncthreads();
    for (int idx = tid; idx < 1024; idx += 256) {
      int r = idx >> 3, cg = idx & 7, c = k0 + cg * 4;
      if (c < C4) stpk4(&sA[r * KS + cg * 4], *(const float4*)(srow + (size_t)r * (H_ * C4) + c));
      else stz8(&sA[r * KS + cg * 4]);
    }
    for (int idx = tid; idx < C4 * 8; idx += 256) {
      int dd = idx >> 3, cg = idx & 7, c = k0 + cg * 4;
      if (c < C4) stpk4(&sB[dd * KS + cg * 4], *(const float4*)(wb + dd * C4 + c));
      else stz8(&sB[dd * KS + cg * 4]);
    }
    __syncthreads();
    const bf16_t* ap = &sA[(wid * 32 + l15) * KS + q * 8];
    bf16x8 a0 = *(const bf16x8*)ap;
    bf16x8 a1 = *(const bf16x8*)(ap + 16 * KS);
    for (int f = 0; f < NF; f++) {
      bf16x8 bb = *(const bf16x8*)&sB[(16 * f + l15) * KS + q * 8];
      acc[0][f] = mfma_bf16(a0, bb, acc[0][f]);
      acc[1][f] = mfma_bf16(a1, bb, acc[1][f]);
    }
  }
  // transposed write: Qt row c = 16f+l15, cols n = n0 + wid*32 + 16i + q*4 + r (4 packed)
  bf16_t* qbh = qout + (size_t)(b * H_ + h) * C4 * 4096;
  for (int i = 0; i < 2; i++)
    for (int f = 0; f < NF; f++) {
      bf16_t pk[4];
      for (int r = 0; r < 4; r++) pk[r] = (bf16_t)acc[i][f][r];
      *(uint2*)(qbh + (size_t)(16 * f + l15) * 4096 + n0 + wid * 32 + 16 * i + q * 4) =
          *(const uint2*)pk;
    }
}

// ============ K/V projection, merged per modality; 512 threads, 128 rows/block.
// T14 split staging: issue global loads for step t+1 before MFMA(t); ds_write after barrier.
__global__ __launch_bounds__(512) void k_proj_kv(
    const bf16_t* __restrict__ G, const bf16_t* __restrict__ Wkvb,
    bf16_t* __restrict__ Kt0, bf16_t* __restrict__ V0,
    bf16_t* __restrict__ Kt1, bf16_t* __restrict__ V1) {
  const int mod = blockIdx.y;
  const bf16_t* src = G + (size_t)mod * ((size_t)B_ * H_ * N_ * 240);
  const bf16_t* wK = Wkvb + (size_t)(2 * mod) * 57600;
  const bf16_t* wV = Wkvb + (size_t)(2 * mod + 1) * 57600;
  bf16_t* Kt = mod ? Kt1 : Kt0;
  bf16_t* V = mod ? V1 : V0;
  const int m0 = blockIdx.x * 128;
  const int bh = m0 >> 12, n0 = m0 & 4095;
  const int tid = threadIdx.x, lane = tid & 63, wid = tid >> 6;  // wid 0..7
  const int l15 = lane & 15, q = lane >> 4;
  __shared__ bf16_t sA[128 * KS];
  __shared__ bf16_t sB[2][240 * KS];
  const f32x4 fz = {0.f, 0.f, 0.f, 0.f};
  f32x4 accK[15], accV[15];
  for (int f = 0; f < 15; f++) { accK[f] = fz; accV[f] = fz; }
  const bf16_t* arow = src + (size_t)m0 * 240;
  const uint4 z4 = make_uint4(0u, 0u, 0u, 0u);

  const int ar = tid >> 2, ag = tid & 3;          // A row / col-group
  int bm[4], bd[4], bg[4];                        // B tile (K/V), row, col-group
#pragma unroll
  for (int j = 0; j < 4; j++) {
    int idx = tid + 512 * j;
    bm[j] = idx >= 960;
    int jj = idx - (bm[j] ? 960 : 0);
    bd[j] = jj >> 2; bg[j] = jj & 3;
  }
  uint4 ra, rb0, rb1, rb2, rb3;

#define KV_LOAD(K0)                                                                    \
  {                                                                                    \
    int c = (K0) + ag * 8;                                                             \
    ra = (c < 240) ? *(const uint4*)(arow + (size_t)ar * 240 + c) : z4;                \
    int c0_ = (K0) + bg[0] * 8;                                                        \
    rb0 = (c0_ < 240) ? *(const uint4*)((bm[0] ? wV : wK) + bd[0] * 240 + c0_) : z4;   \
    int c1_ = (K0) + bg[1] * 8;                                                        \
    rb1 = (c1_ < 240) ? *(const uint4*)((bm[1] ? wV : wK) + bd[1] * 240 + c1_) : z4;   \
    int c2_ = (K0) + bg[2] * 8;                                                        \
    rb2 = (c2_ < 240) ? *(const uint4*)((bm[2] ? wV : wK) + bd[2] * 240 + c2_) : z4;   \
    if (tid < 384) {                                                                   \
      int c3_ = (K0) + bg[3] * 8;                                                      \
      rb3 = (c3_ < 240) ? *(const uint4*)((bm[3] ? wV : wK) + bd[3] * 240 + c3_) : z4; \
    }                                                                                  \
  }
#define KV_WRITE()                                                                     \
  {                                                                                    \
    *(uint4*)&sA[ar * KS + ag * 8] = ra;                                               \
    *(uint4*)&sB[bm[0]][bd[0] * KS + bg[0] * 8] = rb0;                                 \
    *(uint4*)&sB[bm[1]][bd[1] * KS + bg[1] * 8] = rb1;                                 \
    *(uint4*)&sB[bm[2]][bd[2] * KS + bg[2] * 8] = rb2;                                 \
    if (tid < 384) *(uint4*)&sB[bm[3]][bd[3] * KS + bg[3] * 8] = rb3;                  \
  }

  KV_LOAD(0);
  KV_WRITE();
  for (int t = 0; t < 8; t++) {
    if (t < 7) KV_LOAD((t + 1) * 32);  // issue next-step loads; latency hides under MFMA
    __syncthreads();                   // staged writes visible
    bf16x8 a = *(const bf16x8*)&sA[(wid * 16 + l15) * KS + q * 8];
#pragma unroll
    for (int f = 0; f < 15; f++) {
      bf16x8 bk = *(const bf16x8*)&sB[0][(16 * f + l15) * KS + q * 8];
      bf16x8 bv = *(const bf16x8*)&sB[1][(16 * f + l15) * KS + q * 8];
      accK[f] = mfma_bf16(a, bk, accK[f]);
      accV[f] = mfma_bf16(a, bv, accV[f]);
    }
    __syncthreads();                   // all reads done before overwrite
    if (t < 7) KV_WRITE();             // vmcnt drain + ds_write (post-MFMA)
  }
#undef KV_LOAD
#undef KV_WRITE

  // K^T: rows k=16f+l15, cols n (4 consecutive packed in b64)
  for (int f = 0; f < 15; f++) {
    bf16_t pk[4];
    for (int r = 0; r < 4; r++) pk[r] = (bf16_t)accK[f][r];
    bf16_t* dst = Kt + ((size_t)bh * 240 + 16 * f + l15) * 4096 + n0 + wid * 16 + q * 4;
    *(uint2*)dst = *(const uint2*)pk;
  }
  // V n-major
  bf16_t* orow = V + ((size_t)bh * N_ + n0) * 240;
  for (int f = 0; f < 15; f++)
    for (int r = 0; r < 4; r++) {
      int mm = wid * 16 + q * 4 + r;
      orow[(size_t)mm * 240 + 16 * f + l15] = (bf16_t)accV[f][r];
    }
}

// ============ scores, ALL scales fused: one block per (bh, mod, 256-col n-chunk)
// stages the K^T chunk ONCE and computes all 240 Q-rows against it (frag boundaries
// align with scale boundaries 16|48|112). 8 waves; wave w owns c-frags {w, w+8}.
// Partial sums atomicAdd'ed into probs (memset beforehand).
__global__ __launch_bounds__(512) void k_scores_all(
    const bf16_t* __restrict__ Qb, const bf16_t* __restrict__ Kt0,
    const bf16_t* __restrict__ Kt1, float* __restrict__ probs) {
  const size_t KV1 = (size_t)B_ * H_ * N_ * 240;
  const size_t PB1 = (size_t)B_ * H_ * 240 * 240;
  const int qcum[4] = {0, 16, 48, 112};
  const int bh = blockIdx.x;
  const int mod = blockIdx.y >> 4, chunk = blockIdx.y & 15;
  const int ch0 = chunk * 256;
  const bf16_t* ktp = mod ? Kt0 : Kt1;  // cross-modal
  const int tid = threadIdx.x, lane = tid & 63, wid = tid >> 6;  // wid 0..7
  const int l15 = lane & 15, q = lane >> 4;
  __shared__ bf16_t sQ[240 * KS];
  __shared__ bf16_t sK[240 * KS];
  const f32x4 fz = {0.f, 0.f, 0.f, 0.f};
  f32x4 acc[2][15];
  for (int i = 0; i < 2; i++) for (int f = 0; f < 15; f++) acc[i][f] = fz;

  // staging geometry: item idx -> row idx>>2 (0..239), col-group idx&3 (8 cols each).
  // thread handles rows row0 = tid>>2 and row1 = row0+128 (row1 valid iff tid<448).
  const int row0 = tid >> 2, g8 = (tid & 3) * 8;
  const int row1v = row0 + 128;
  const int row1 = (row1v < 240) ? row1v : 239;  // clamped for safe addr math
  const bool hasR1 = (tid < 448);
  // Qt row pointer: scale region + [bh][c'][4096]
  int s0i = qsc(row0), s1i = qsc(row1);
  const bf16_t* qp0 = Qb + (size_t)mod * KV1 + (size_t)65536 * qcum[s0i] +
                      ((size_t)bh * (16 << s0i) + (row0 - qcum[s0i])) * 4096 + ch0 + g8;
  const bf16_t* qp1 = Qb + (size_t)mod * KV1 + (size_t)65536 * qcum[s1i] +
                      ((size_t)bh * (16 << s1i) + (row1 - qcum[s1i])) * 4096 + ch0 + g8;
  const bf16_t* kp0 = ktp + ((size_t)bh * 240 + row0) * 4096 + ch0 + g8;
  const bf16_t* kp1 = ktp + ((size_t)bh * 240 + row1) * 4096 + ch0 + g8;
  uint4 rq0, rq1, rk0, rk1;

#define SC_LOAD(K0)                                   \
  {                                                   \
    rq0 = *(const uint4*)(qp0 + (K0));                \
    rk0 = *(const uint4*)(kp0 + (K0));                \
    if (hasR1) {                                      \
      rq1 = *(const uint4*)(qp1 + (K0));              \
      rk1 = *(const uint4*)(kp1 + (K0));              \
    }                                                 \
  }
#define SC_WRITE()                                    \
  {                                                   \
    *(uint4*)&sQ[row0 * KS + g8] = rq0;               \
    *(uint4*)&sK[row0 * KS + g8] = rk0;               \
    if (hasR1) {                                      \
      *(uint4*)&sQ[row1v * KS + g8] = rq1;            \
      *(uint4*)&sK[row1v * KS + g8] = rk1;            \
    }                                                 \
  }

  const int cf0 = wid, cf1 = wid + 8;  // c-frags owned by this wave (cf1<15 check)
  SC_LOAD(0);
  SC_WRITE();
  for (int t = 0; t < 8; t++) {
    if (t < 7) SC_LOAD((t + 1) * 32);
    __syncthreads();
    bf16x8 af0 = *(const bf16x8*)&sQ[(16 * cf0 + l15) * KS + q * 8];
    bf16x8 af1;
    if (cf1 < 15) af1 = *(const bf16x8*)&sQ[(16 * cf1 + l15) * KS + q * 8];
#pragma unroll
    for (int f = 0; f < 15; f++) {
      bf16x8 bb = *(const bf16x8*)&sK[(16 * f + l15) * KS + q * 8];
      acc[0][f] = mfma_bf16(af0, bb, acc[0][f]);
      if (cf1 < 15) acc[1][f] = mfma_bf16(af1, bb, acc[1][f]);
    }
    __syncthreads();
    if (t < 7) SC_WRITE();
  }
#undef SC_LOAD
#undef SC_WRITE

  const float rs = 0.0322748612183951f;  // 1/sqrt(960)
  for (int ci = 0; ci < 2; ci++) {
    int cf = wid + 8 * ci;
    if (cf >= 15) continue;
    int cbase = 16 * cf;
    int s = qsc(cbase);
    float* pb = probs + (size_t)mod * PB1 +
                ((size_t)16 * qcum[s] + (size_t)bh * (16 << s)) * 240;
    int crow = cbase - qcum[s] + q * 4;
    for (int f = 0; f < 15; f++)
      for (int r = 0; r < 4; r++)
        atomicAdd(&pb[(size_t)(crow + r) * 240 + 16 * f + l15], acc[ci][f][r] * rs);
  }
}

// ============ InstanceNorm over (c,k) per (b,h), then softmax over k (240)
__global__ __launch_bounds__(256) void k_inorm_softmax(float* __restrict__ p0,
                                                       float* __restrict__ p1, int c4) {
  float* p = (blockIdx.z ? p1 : p0) + (size_t)blockIdx.x * c4 * 240;
  const int tid = threadIdx.x;
  const int tot = c4 * 240;
  float s = 0.f, s2 = 0.f;
  for (int idx = tid; idx < tot; idx += 256) {
    float v = p[idx];
    s += v; s2 += v * v;
  }
#pragma unroll
  for (int off = 32; off > 0; off >>= 1) {
    s += __shfl_xor(s, off);
    s2 += __shfl_xor(s2, off);
  }
  __shared__ float rsum[4], rsum2[4], smv[2];
  const int wid = tid >> 6, lane = tid & 63;
  if (lane == 0) { rsum[wid] = s; rsum2[wid] = s2; }
  __syncthreads();
  if (tid == 0) {
    float ts = rsum[0] + rsum[1] + rsum[2] + rsum[3];
    float ts2 = rsum2[0] + rsum2[1] + rsum2[2] + rsum2[3];
    float mean = ts / tot;
    float var = ts2 / tot - mean * mean;
    smv[0] = mean; smv[1] = rsqrtf(var + 1e-5f);
  }
  __syncthreads();
  const float mean = smv[0], rstd = smv[1];
  for (int c = wid; c < c4; c += 4) {
    float* row = p + (size_t)c * 240;
    float x[4]; float mx = -1e30f;
#pragma unroll
    for (int t = 0; t < 4; t++) {
      int k = lane + 64 * t;
      x[t] = (k < 240) ? (row[k] - mean) * rstd : -1e30f;
      mx = fmaxf(mx, x[t]);
    }
#pragma unroll
    for (int off = 32; off > 0; off >>= 1) mx = fmaxf(mx, __shfl_xor(mx, off));
    float e[4], sum = 0.f;
#pragma unroll
    for (int t = 0; t < 4; t++) {
      int k = lane + 64 * t;
      e[t] = (k < 240) ? expf(x[t] - mx) : 0.f;
      sum += e[t];
    }
#pragma unroll
    for (int off = 32; off > 0; off >>= 1) sum += __shfl_xor(sum, off);
    const float inv = 1.f / sum;
#pragma unroll
    for (int t = 0; t < 4; t++) {
      int k = lane + 64 * t;
      if (k < 240) row[k] = e[t] * inv;
    }
  }
}

// ============ PV: ctx[b,n,chof+h*C4+c] = sum_k P[c,k] * V[bh,n,k]
template <int C4>
__global__ __launch_bounds__(256) void k_pv(
    const float* __restrict__ p0, const bf16_t* __restrict__ v0, bf16_t* __restrict__ c0p,
    const float* __restrict__ p1, const bf16_t* __restrict__ v1, bf16_t* __restrict__ c1p,
    int chof) {
  constexpr int NF = C4 / 16;
  const float* pr = blockIdx.z ? p1 : p0;
  const bf16_t* v = blockIdx.z ? v1 : v0;
  bf16_t* ctx = blockIdx.z ? c1p : c0p;
  const int bh = blockIdx.y, b = bh >> 2, h = bh & 3;
  const int n0 = blockIdx.x * 128;
  const int tid = threadIdx.x, lane = tid & 63, wid = tid >> 6;
  const int l15 = lane & 15, q = lane >> 4;
  __shared__ bf16_t sV[128 * KS];
  __shared__ bf16_t sP[C4 * KS];
  const f32x4 fz = {0.f, 0.f, 0.f, 0.f};
  f32x4 acc[2][NF];
  for (int i = 0; i < 2; i++) for (int f = 0; f < NF; f++) acc[i][f] = fz;
  const bf16_t* vrow = v + ((size_t)bh * N_ + n0) * 240;
  const float* pb = pr + (size_t)bh * C4 * 240;
  for (int k0 = 0; k0 < 256; k0 += 32) {
    __syncthreads();
    for (int idx = tid; idx < 512; idx += 256) {  // V uint4
      int r = idx >> 2, g = idx & 3, k = k0 + g * 8;
      if (k < 240) *(uint4*)&sV[r * KS + g * 8] = *(const uint4*)(vrow + (size_t)r * 240 + k);
      else *(uint4*)&sV[r * KS + g * 8] = make_uint4(0u, 0u, 0u, 0u);
    }
    for (int idx = tid; idx < C4 * 8; idx += 256) {  // P fp32 -> bf16 packed
      int cc = idx >> 3, cg = idx & 7, k = k0 + cg * 4;
      if (k < 240) stpk4(&sP[cc * KS + cg * 4], *(const float4*)(pb + (size_t)cc * 240 + k));
      else stz8(&sP[cc * KS + cg * 4]);
    }
    __syncthreads();
    const bf16_t* ap = &sV[(wid * 32 + l15) * KS + q * 8];
    bf16x8 a0 = *(const bf16x8*)ap;
    bf16x8 a1 = *(const bf16x8*)(ap + 16 * KS);
    for (int f = 0; f < NF; f++) {
      bf16x8 bb = *(const bf16x8*)&sP[(16 * f + l15) * KS + q * 8];
      acc[0][f] = mfma_bf16(a0, bb, acc[0][f]);
      acc[1][f] = mfma_bf16(a1, bb, acc[1][f]);
    }
  }
  bf16_t* crow = ctx + ((size_t)b * N_ + n0) * 960 + chof + h * C4;
  for (int i = 0; i < 2; i++)
    for (int f = 0; f < NF; f++)
      for (int r = 0; r < 4; r++) {
        int mm = wid * 32 + 16 * i + q * 4 + r;
        crow[(size_t)mm * 960 + 16 * f + l15] = (bf16_t)acc[i][f][r];
      }
}

// ============ out[b,n,obase+d] = sum_c ctx[b,n,chof+c] * Wob[d,c]   (fp32 out)
template <int CS>
__global__ __launch_bounds__(256) void k_wout(
    const bf16_t* __restrict__ c0p, const bf16_t* __restrict__ w0, int ob0,
    const bf16_t* __restrict__ c1p, const bf16_t* __restrict__ w1, int ob1,
    float* __restrict__ out, int chof) {
  constexpr int DT = (CS < 128) ? CS : 128;
  constexpr int NF = DT / 16;
  constexpr int DB = CS / DT;
  const int mod = blockIdx.z / DB, dch = blockIdx.z % DB;
  const bf16_t* ctx = mod ? c1p : c0p;
  const bf16_t* w = mod ? w1 : w0;
  const int obase = (mod ? ob1 : ob0) + dch * DT;
  const int m0 = blockIdx.x * 128;
  const int b = m0 >> 12, n0 = m0 & 4095;
  const int tid = threadIdx.x, lane = tid & 63, wid = tid >> 6;
  const int l15 = lane & 15, q = lane >> 4;
  __shared__ bf16_t sA[128 * KS];
  __shared__ bf16_t sB[DT * KS];
  const f32x4 fz = {0.f, 0.f, 0.f, 0.f};
  f32x4 acc[2][NF];
  for (int i = 0; i < 2; i++) for (int f = 0; f < NF; f++) acc[i][f] = fz;
  const bf16_t* arow = ctx + ((size_t)b * N_ + n0) * 960 + chof;
  const bf16_t* wb = w + (size_t)dch * DT * CS;
  for (int k0 = 0; k0 < CS; k0 += 32) {
    __syncthreads();
    for (int idx = tid; idx < 512; idx += 256) {  // ctx uint4
      int r = idx >> 2, g = idx & 3, k = k0 + g * 8;
      *(uint4*)&sA[r * KS + g * 8] = *(const uint4*)(arow + (size_t)r * 960 + k);
    }
    for (int idx = tid; idx < DT * 4; idx += 256) {  // W uint4 (bf16 pre-converted)
      int dd = idx >> 2, g = idx & 3, k = k0 + g * 8;
      *(uint4*)&sB[dd * KS + g * 8] = *(const uint4*)(wb + (size_t)dd * CS + k);
    }
    __syncthreads();
    const bf16_t* ap = &sA[(wid * 32 + l15) * KS + q * 8];
    bf16x8 a0 = *(const bf16x8*)ap;
    bf16x8 a1 = *(const bf16x8*)(ap + 16 * KS);
    for (int f = 0; f < NF; f++) {
      bf16x8 bb = *(const bf16x8*)&sB[(16 * f + l15) * KS + q * 8];
      acc[0][f] = mfma_bf16(a0, bb, acc[0][f]);
      acc[1][f] = mfma_bf16(a1, bb, acc[1][f]);
    }
  }
  float* orow = out + ((size_t)b * N_ + n0) * 1920 + obase;
  for (int i = 0; i < 2; i++)
    for (int f = 0; f < NF; f++)
      for (int r = 0; r < 4; r++) {
        int mm = wid * 32 + 16 * i + q * 4 + r;
        orow[(size_t)mm * 1920 + 16 * f + l15] = acc[i][f][r];
      }
}

extern "C" void kernel_launch(void* const* d_in, const int* in_sizes, int n_in,
                              void* d_out, int out_size, void* d_ws, size_t ws_size,
                              hipStream_t stream) {
  (void)in_sizes; (void)n_in; (void)out_size; (void)ws_size;
  const float* emb[2][4];
  const float* wq[2][4];
  const float* wo[2][4];
  for (int s = 0; s < 4; s++) {
    emb[0][s] = (const float*)d_in[2 * s];
    emb[1][s] = (const float*)d_in[2 * s + 1];
    wq[0][s] = (const float*)d_in[10 + 4 * s];
    wq[1][s] = (const float*)d_in[11 + 4 * s];
    wo[0][s] = (const float*)d_in[12 + 4 * s];
    wo[1][s] = (const float*)d_in[13 + 4 * s];
  }
  const float* emb_all = (const float*)d_in[8];
  const float* emb_alld = (const float*)d_in[9];
  const float* wkp = (const float*)d_in[26];
  const float* wvp = (const float*)d_in[27];
  const float* wkdp = (const float*)d_in[28];
  const float* wvdp = (const float*)d_in[29];
  float* out = (float*)d_out;

  // ws layout: [Kt0 Kt1 V0 V1 Q0/ctx0 Q1/ctx1 : bf16, 6*KV1] [probs fp32 2*PB1] [Wkvb][Wob]
  // Q region additionally hosts G (kvsplit bf16) before proj_q runs.
  bf16_t* w16 = (bf16_t*)d_ws;
  const size_t KV1 = (size_t)B_ * H_ * N_ * 240;  // 15,728,640
  const size_t PB1 = (size_t)B_ * H_ * 240 * 240;
  bf16_t* Kt0 = w16;
  bf16_t* Kt1 = w16 + KV1;
  bf16_t* V0 = w16 + 2 * KV1;
  bf16_t* V1 = w16 + 3 * KV1;
  bf16_t* Qb = w16 + 4 * KV1;              // G, then Qt, then ctx
  float* probs = (float*)(w16 + 6 * KV1);
  bf16_t* Wkvb = (bf16_t*)(probs + 2 * PB1);
  bf16_t* Wob = Wkvb + 230400;
  const int qcum[4] = {0, 16, 48, 112};
  const int chof[4] = {0, 64, 192, 448};
  const int soff[4] = {0, 4096, 20480, 86016};
  const dim3 blk(256);

  k_prep_w<<<dim3(256), blk, 0, stream>>>(wkp, wvp, wkdp, wvdp,
      wo[0][0], wo[0][1], wo[0][2], wo[0][3], wo[1][0], wo[1][1], wo[1][2], wo[1][3],
      Wkvb, Wob);
  hipMemsetAsync(probs, 0, 2 * PB1 * sizeof(float), stream);

  // --- kvsplit prepass: G (bf16, [mod][bh][n][240]) into the Q region ---
  k_kvsplit<<<dim3(2048), blk, 0, stream>>>(emb_all, emb_alld, Qb);
  // --- K/V projections (merged K+V per modality; K transposed; 512-thread blocks) ---
  k_proj_kv<<<dim3(B_ * H_ * N_ / 128, 2), dim3(512), 0, stream>>>(
      Qb, Wkvb, Kt0, V0, Kt1, V1);
  // --- Q projections (overwrite G with Qt; G is dead after proj_kv) ---
  for (int s = 0; s < 4; s++) {
    bf16_t* q0 = Qb + (size_t)B_ * H_ * N_ * qcum[s];
    bf16_t* q1 = q0 + KV1;
    dim3 g(B_ * N_ / 128, H_, 2);
    switch (s) {
      case 0: k_proj_q<16><<<g, blk, 0, stream>>>(emb[0][s], wq[0][s], q0, emb[1][s], wq[1][s], q1); break;
      case 1: k_proj_q<32><<<g, blk, 0, stream>>>(emb[0][s], wq[0][s], q0, emb[1][s], wq[1][s], q1); break;
      case 2: k_proj_q<64><<<g, blk, 0, stream>>>(emb[0][s], wq[0][s], q0, emb[1][s], wq[1][s], q1); break;
      case 3: k_proj_q<128><<<g, blk, 0, stream>>>(emb[0][s], wq[0][s], q0, emb[1][s], wq[1][s], q1); break;
    }
  }
  // --- scores, all scales fused: one kernel reads each K^T column exactly once ---
  k_scores_all<<<dim3(B_ * H_, 32), dim3(512), 0, stream>>>(Qb, Kt0, Kt1, probs);
  // --- InstanceNorm + softmax ---
  for (int s = 0; s < 4; s++) {
    float* p0 = probs + (size_t)B_ * H_ * qcum[s] * 240;
    float* p1 = p0 + PB1;
    k_inorm_softmax<<<dim3(B_ * H_, 1, 2), blk, 0, stream>>>(p0, p1, 16 << s);
  }
  // --- PV (optical uses Vd=V1, DSM uses V0); ctx overlays Q region ---
  for (int s = 0; s < 4; s++) {
    float* p0 = probs + (size_t)B_ * H_ * qcum[s] * 240;
    float* p1 = p0 + PB1;
    bf16_t* cx0 = Qb;
    bf16_t* cx1 = Qb + KV1;
    dim3 g(N_ / 128, B_ * H_, 2);
    switch (s) {
      case 0: k_pv<16><<<g, blk, 0, stream>>>(p0, V1, cx0, p1, V0, cx1, chof[s]); break;
      case 1: k_pv<32><<<g, blk, 0, stream>>>(p0, V1, cx0, p1, V0, cx1, chof[s]); break;
      case 2: k_pv<64><<<g, blk, 0, stream>>>(p0, V1, cx0, p1, V0, cx1, chof[s]); break;
      case 3: k_pv<128><<<g, blk, 0, stream>>>(p0, V1, cx0, p1, V0, cx1, chof[s]); break;
    }
  }
  // --- output projection (bf16 weights) ---
  for (int s = 0; s < 4; s++) {
    const bf16_t* cx0 = Qb;
    const bf16_t* cx1 = Qb + KV1;
    const bf16_t* w0 = Wob + soff[s];
    const bf16_t* w1 = Wob + 348160 + soff[s];
    const int cs = 64 << s;
    const int db = (cs < 128) ? 1 : cs / 128;
    dim3 g(B_ * N_ / 128, 1, 2 * db);
    switch (s) {
      case 0: k_wout<64><<<g, blk, 0, stream>>>(cx0, w0, chof[s], cx1, w1, 960 + chof[s], out, chof[s]); break;
      case 1: k_wout<128><<<g, blk, 0, stream>>>(cx0, w0, chof[s], cx1, w1, 960 + chof[s], out, chof[s]); break;
      case 2: k_wout<256><<<g, blk, 0, stream>>>(cx0, w0, chof[s], cx1, w1, 960 + chof[s], out, chof[s]); break;
      case 3: k_wout<512><<<g, blk, 0, stream>>>(cx0, w0, chof[s], cx1, w1, 960 + chof[s], out, chof[s]); break;
    }
  }
}

// Round 5
// 826.604 us; speedup vs baseline: 1.5160x; 1.1034x over previous
//
#include <hip/hip_runtime.h>
#include <hip/hip_bf16.h>

typedef __bf16 bf16_t;
typedef __bf16 bf16x8 __attribute__((ext_vector_type(8)));
typedef float f32x4 __attribute__((ext_vector_type(4)));

static constexpr int B_ = 4, N_ = 4096, H_ = 4;
static constexpr int KS = 40;  // LDS k-stride (bf16): 80 B rows, 16B-aligned b128, 2-way max on reads

__device__ __forceinline__ f32x4 mfma_bf16(bf16x8 a, bf16x8 b, f32x4 c) {
  return __builtin_amdgcn_mfma_f32_16x16x32_bf16(a, b, c, 0, 0, 0);
}

// convert float4 -> 4 bf16 in registers, single 8 B LDS store (no scalar ds_write_b16)
__device__ __forceinline__ void stpk4(bf16_t* d, float4 v) {
  bf16_t t[4] = {(bf16_t)v.x, (bf16_t)v.y, (bf16_t)v.z, (bf16_t)v.w};
  *(uint2*)d = *(const uint2*)t;
}
__device__ __forceinline__ void stz8(bf16_t* d) { *(uint2*)d = make_uint2(0u, 0u); }

// kvsplit gather: quarter h, local col c (0..239) -> emb_all column
__device__ __forceinline__ int kvg(int h, int c) {
  if (c < 16)  return h * 16 + c;
  if (c < 48)  return 64 + h * 32 + c - 16;
  if (c < 112) return 192 + h * 64 + c - 48;
  return 448 + h * 128 + c - 112;
}

// global Q/P row r (0..239) -> scale index
__device__ __forceinline__ int qsc(int r) { return (r < 16) ? 0 : (r < 48) ? 1 : (r < 112) ? 2 : 3; }

// ============ weight pre-convert fp32 -> bf16 (one pass, ~230k f4 items)
__global__ __launch_bounds__(256) void k_prep_w(
    const float* __restrict__ wk, const float* __restrict__ wv,
    const float* __restrict__ wkd, const float* __restrict__ wvd,
    const float* __restrict__ wo00, const float* __restrict__ wo01,
    const float* __restrict__ wo02, const float* __restrict__ wo03,
    const float* __restrict__ wo10, const float* __restrict__ wo11,
    const float* __restrict__ wo12, const float* __restrict__ wo13,
    bf16_t* __restrict__ Wkvb, bf16_t* __restrict__ Wob) {
  const float* wkv[4] = {wk, wv, wkd, wvd};
  const float* wo[2][4] = {{wo00, wo01, wo02, wo03}, {wo10, wo11, wo12, wo13}};
  const int soff_f4[5] = {0, 1024, 5120, 21504, 87040};
  for (int i = blockIdx.x * 256 + threadIdx.x; i < 231680; i += gridDim.x * 256) {
    if (i < 57600) {  // kv weights: 4 x 14400 f4
      int t = i / 14400, r = i - t * 14400;
      float4 v = *(const float4*)(wkv[t] + r * 4);
      stpk4(Wkvb + (size_t)t * 57600 + r * 4, v);
    } else {  // wout: 2 x 87040 f4
      int j = i - 57600;
      int mod = j / 87040, jr = j - mod * 87040;
      int s = (jr < 1024) ? 0 : (jr < 5120) ? 1 : (jr < 21504) ? 2 : 3;
      float4 v = *(const float4*)(wo[mod][s] + (jr - soff_f4[s]) * 4);
      stpk4(Wob + (size_t)mod * 348160 + jr * 4, v);
    }
  }
}

// ============ kvsplit prepass: emb_all fp32 [b,n,960] -> G bf16 [mod][bh][n][240]
__global__ __launch_bounds__(256) void k_kvsplit(
    const float* __restrict__ eA, const float* __restrict__ eB,
    bf16_t* __restrict__ G) {
  const int TOT = 2 * 16 * 4096 * 30;  // 3,932,160 chunks
  for (int i = blockIdx.x * 256 + threadIdx.x; i < TOT; i += gridDim.x * 256) {
    int t = i / 30;                 // row index: mod*65536 + bh*4096 + n
    int cg = i - t * 30;
    int mod = t >> 16;
    int row = t & 65535;            // bh*4096 + n
    int bh = row >> 12, n = row & 4095;
    int b = bh >> 2, h = bh & 3;
    int col = kvg(h, cg * 8);
    const float* src = (mod ? eB : eA) + ((size_t)b * N_ + n) * 960 + col;
    float4 v0 = *(const float4*)src;
    float4 v1 = *(const float4*)(src + 4);
    bf16_t o[8] = {(bf16_t)v0.x, (bf16_t)v0.y, (bf16_t)v0.z, (bf16_t)v0.w,
                   (bf16_t)v1.x, (bf16_t)v1.y, (bf16_t)v1.z, (bf16_t)v1.w};
    *(uint4*)(G + (size_t)t * 240 + cg * 8) = *(const uint4*)o;
  }
}

// ============ Q projection: Q[bh,n,d] -> written TRANSPOSED Qt[bh][d][4096] (packed uint2)
template <int C4>
__global__ __launch_bounds__(256) void k_proj_q(
    const float* __restrict__ e0, const float* __restrict__ w0, bf16_t* __restrict__ o0,
    const float* __restrict__ e1, const float* __restrict__ w1, bf16_t* __restrict__ o1) {
  constexpr int KP = (C4 < 32) ? 32 : C4;
  constexpr int NF = C4 / 16;
  const float* emb = blockIdx.z ? e1 : e0;
  const float* wq = blockIdx.z ? w1 : w0;
  bf16_t* qout = blockIdx.z ? o1 : o0;
  const int h = blockIdx.y;
  const int m0 = blockIdx.x * 128;
  const int b = m0 >> 12, n0 = m0 & 4095;
  const int tid = threadIdx.x, lane = tid & 63, wid = tid >> 6;
  const int l15 = lane & 15, q = lane >> 4;
  __shared__ bf16_t sA[128 * KS];
  __shared__ bf16_t sB[C4 * KS];
  const f32x4 fz = {0.f, 0.f, 0.f, 0.f};
  f32x4 acc[2][NF];
  for (int i = 0; i < 2; i++) for (int f = 0; f < NF; f++) acc[i][f] = fz;
  const float* srow = emb + ((size_t)b * N_ + n0) * (H_ * C4) + h * C4;
  const float* wb = wq + h * C4 * C4;
  for (int k0 = 0; k0 < KP; k0 += 32) {
    __syncthreads();
    for (int idx = tid; idx < 1024; idx += 256) {
      int r = idx >> 3, cg = idx & 7, c = k0 + cg * 4;
      if (c < C4) stpk4(&sA[r * KS + cg * 4], *(const float4*)(srow + (size_t)r * (H_ * C4) + c));
      else stz8(&sA[r * KS + cg * 4]);
    }
    for (int idx = tid; idx < C4 * 8; idx += 256) {
      int dd = idx >> 3, cg = idx & 7, c = k0 + cg * 4;
      if (c < C4) stpk4(&sB[dd * KS + cg * 4], *(const float4*)(wb + dd * C4 + c));
      else stz8(&sB[dd * KS + cg * 4]);
    }
    __syncthreads();
    const bf16_t* ap = &sA[(wid * 32 + l15) * KS + q * 8];
    bf16x8 a0 = *(const bf16x8*)ap;
    bf16x8 a1 = *(const bf16x8*)(ap + 16 * KS);
    for (int f = 0; f < NF; f++) {
      bf16x8 bb = *(const bf16x8*)&sB[(16 * f + l15) * KS + q * 8];
      acc[0][f] = mfma_bf16(a0, bb, acc[0][f]);
      acc[1][f] = mfma_bf16(a1, bb, acc[1][f]);
    }
  }
  // transposed write: Qt row c = 16f+l15, cols n = n0 + wid*32 + 16i + q*4 + r (4 packed)
  bf16_t* qbh = qout + (size_t)(b * H_ + h) * C4 * 4096;
  for (int i = 0; i < 2; i++)
    for (int f = 0; f < NF; f++) {
      bf16_t pk[4];
      for (int r = 0; r < 4; r++) pk[r] = (bf16_t)acc[i][f][r];
      *(uint2*)(qbh + (size_t)(16 * f + l15) * 4096 + n0 + wid * 32 + 16 * i + q * 4) =
          *(const uint2*)pk;
    }
}

// ============ K/V projection, merged per modality; 512 threads, 128 rows/block.
// T14 split staging: issue global loads for step t+1 before MFMA(t); ds_write after barrier.
__global__ __launch_bounds__(512) void k_proj_kv(
    const bf16_t* __restrict__ G, const bf16_t* __restrict__ Wkvb,
    bf16_t* __restrict__ Kt0, bf16_t* __restrict__ V0,
    bf16_t* __restrict__ Kt1, bf16_t* __restrict__ V1) {
  const int mod = blockIdx.y;
  const bf16_t* src = G + (size_t)mod * ((size_t)B_ * H_ * N_ * 240);
  const bf16_t* wK = Wkvb + (size_t)(2 * mod) * 57600;
  const bf16_t* wV = Wkvb + (size_t)(2 * mod + 1) * 57600;
  bf16_t* Kt = mod ? Kt1 : Kt0;
  bf16_t* V = mod ? V1 : V0;
  const int m0 = blockIdx.x * 128;
  const int bh = m0 >> 12, n0 = m0 & 4095;
  const int tid = threadIdx.x, lane = tid & 63, wid = tid >> 6;  // wid 0..7
  const int l15 = lane & 15, q = lane >> 4;
  __shared__ bf16_t sA[128 * KS];
  __shared__ bf16_t sB[2][240 * KS];
  const f32x4 fz = {0.f, 0.f, 0.f, 0.f};
  f32x4 accK[15], accV[15];
  for (int f = 0; f < 15; f++) { accK[f] = fz; accV[f] = fz; }
  const bf16_t* arow = src + (size_t)m0 * 240;
  const uint4 z4 = make_uint4(0u, 0u, 0u, 0u);

  const int ar = tid >> 2, ag = tid & 3;          // A row / col-group
  int bm[4], bd[4], bg[4];                        // B tile (K/V), row, col-group
#pragma unroll
  for (int j = 0; j < 4; j++) {
    int idx = tid + 512 * j;
    bm[j] = idx >= 960;
    int jj = idx - (bm[j] ? 960 : 0);
    bd[j] = jj >> 2; bg[j] = jj & 3;
  }
  uint4 ra, rb0, rb1, rb2, rb3;

#define KV_LOAD(K0)                                                                    \
  {                                                                                    \
    int c = (K0) + ag * 8;                                                             \
    ra = (c < 240) ? *(const uint4*)(arow + (size_t)ar * 240 + c) : z4;                \
    int c0_ = (K0) + bg[0] * 8;                                                        \
    rb0 = (c0_ < 240) ? *(const uint4*)((bm[0] ? wV : wK) + bd[0] * 240 + c0_) : z4;   \
    int c1_ = (K0) + bg[1] * 8;                                                        \
    rb1 = (c1_ < 240) ? *(const uint4*)((bm[1] ? wV : wK) + bd[1] * 240 + c1_) : z4;   \
    int c2_ = (K0) + bg[2] * 8;                                                        \
    rb2 = (c2_ < 240) ? *(const uint4*)((bm[2] ? wV : wK) + bd[2] * 240 + c2_) : z4;   \
    if (tid < 384) {                                                                   \
      int c3_ = (K0) + bg[3] * 8;                                                      \
      rb3 = (c3_ < 240) ? *(const uint4*)((bm[3] ? wV : wK) + bd[3] * 240 + c3_) : z4; \
    }                                                                                  \
  }
#define KV_WRITE()                                                                     \
  {                                                                                    \
    *(uint4*)&sA[ar * KS + ag * 8] = ra;                                               \
    *(uint4*)&sB[bm[0]][bd[0] * KS + bg[0] * 8] = rb0;                                 \
    *(uint4*)&sB[bm[1]][bd[1] * KS + bg[1] * 8] = rb1;                                 \
    *(uint4*)&sB[bm[2]][bd[2] * KS + bg[2] * 8] = rb2;                                 \
    if (tid < 384) *(uint4*)&sB[bm[3]][bd[3] * KS + bg[3] * 8] = rb3;                  \
  }

  KV_LOAD(0);
  KV_WRITE();
  for (int t = 0; t < 8; t++) {
    if (t < 7) KV_LOAD((t + 1) * 32);  // issue next-step loads; latency hides under MFMA
    __syncthreads();                   // staged writes visible
    bf16x8 a = *(const bf16x8*)&sA[(wid * 16 + l15) * KS + q * 8];
#pragma unroll
    for (int f = 0; f < 15; f++) {
      bf16x8 bk = *(const bf16x8*)&sB[0][(16 * f + l15) * KS + q * 8];
      bf16x8 bv = *(const bf16x8*)&sB[1][(16 * f + l15) * KS + q * 8];
      accK[f] = mfma_bf16(a, bk, accK[f]);
      accV[f] = mfma_bf16(a, bv, accV[f]);
    }
    __syncthreads();                   // all reads done before overwrite
    if (t < 7) KV_WRITE();             // vmcnt drain + ds_write (post-MFMA)
  }
#undef KV_LOAD
#undef KV_WRITE

  // K^T: rows k=16f+l15, cols n (4 consecutive packed in b64)
  for (int f = 0; f < 15; f++) {
    bf16_t pk[4];
    for (int r = 0; r < 4; r++) pk[r] = (bf16_t)accK[f][r];
    bf16_t* dst = Kt + ((size_t)bh * 240 + 16 * f + l15) * 4096 + n0 + wid * 16 + q * 4;
    *(uint2*)dst = *(const uint2*)pk;
  }
  // V n-major
  bf16_t* orow = V + ((size_t)bh * N_ + n0) * 240;
  for (int f = 0; f < 15; f++)
    for (int r = 0; r < 4; r++) {
      int mm = wid * 16 + q * 4 + r;
      orow[(size_t)mm * 240 + 16 * f + l15] = (bf16_t)accV[f][r];
    }
}

// ============ scores, ALL scales fused: one block per (bh, mod, 512-col n-chunk)
// stages the K^T chunk ONCE and computes all 240 Q-rows against it (frag boundaries
// align with scale boundaries 16|48|112). 8 waves; wave w owns c-frags {w, w+8}.
// 8 chunks (not 16): halves the atomicAdd traffic, which R4 counters showed dominant.
__global__ __launch_bounds__(512) void k_scores_all(
    const bf16_t* __restrict__ Qb, const bf16_t* __restrict__ Kt0,
    const bf16_t* __restrict__ Kt1, float* __restrict__ probs) {
  const size_t KV1 = (size_t)B_ * H_ * N_ * 240;
  const size_t PB1 = (size_t)B_ * H_ * 240 * 240;
  const int qcum[4] = {0, 16, 48, 112};
  const int bh = blockIdx.x;
  const int mod = blockIdx.y >> 3, chunk = blockIdx.y & 7;
  const int ch0 = chunk * 512;
  const bf16_t* ktp = mod ? Kt0 : Kt1;  // cross-modal
  const int tid = threadIdx.x, lane = tid & 63, wid = tid >> 6;  // wid 0..7
  const int l15 = lane & 15, q = lane >> 4;
  __shared__ bf16_t sQ[240 * KS];
  __shared__ bf16_t sK[240 * KS];
  const f32x4 fz = {0.f, 0.f, 0.f, 0.f};
  f32x4 acc[2][15];
  for (int i = 0; i < 2; i++) for (int f = 0; f < 15; f++) acc[i][f] = fz;

  // staging geometry: thread handles rows row0 = tid>>2 and row1 = row0+128 (iff tid<448).
  const int row0 = tid >> 2, g8 = (tid & 3) * 8;
  const int row1v = row0 + 128;
  const int row1 = (row1v < 240) ? row1v : 239;  // clamped for safe addr math
  const bool hasR1 = (tid < 448);
  int s0i = qsc(row0), s1i = qsc(row1);
  const bf16_t* qp0 = Qb + (size_t)mod * KV1 + (size_t)65536 * qcum[s0i] +
                      ((size_t)bh * (16 << s0i) + (row0 - qcum[s0i])) * 4096 + ch0 + g8;
  const bf16_t* qp1 = Qb + (size_t)mod * KV1 + (size_t)65536 * qcum[s1i] +
                      ((size_t)bh * (16 << s1i) + (row1 - qcum[s1i])) * 4096 + ch0 + g8;
  const bf16_t* kp0 = ktp + ((size_t)bh * 240 + row0) * 4096 + ch0 + g8;
  const bf16_t* kp1 = ktp + ((size_t)bh * 240 + row1) * 4096 + ch0 + g8;
  uint4 rq0, rq1, rk0, rk1;

#define SC_LOAD(K0)                                   \
  {                                                   \
    rq0 = *(const uint4*)(qp0 + (K0));                \
    rk0 = *(const uint4*)(kp0 + (K0));                \
    if (hasR1) {                                      \
      rq1 = *(const uint4*)(qp1 + (K0));              \
      rk1 = *(const uint4*)(kp1 + (K0));              \
    }                                                 \
  }
#define SC_WRITE()                                    \
  {                                                   \
    *(uint4*)&sQ[row0 * KS + g8] = rq0;               \
    *(uint4*)&sK[row0 * KS + g8] = rk0;               \
    if (hasR1) {                                      \
      *(uint4*)&sQ[row1v * KS + g8] = rq1;            \
      *(uint4*)&sK[row1v * KS + g8] = rk1;            \
    }                                                 \
  }

  const int cf0 = wid, cf1 = wid + 8;  // c-frags owned by this wave (cf1<15 check)
  SC_LOAD(0);
  SC_WRITE();
  for (int t = 0; t < 16; t++) {
    if (t < 15) SC_LOAD((t + 1) * 32);
    __syncthreads();
    bf16x8 af0 = *(const bf16x8*)&sQ[(16 * cf0 + l15) * KS + q * 8];
    bf16x8 af1;
    if (cf1 < 15) af1 = *(const bf16x8*)&sQ[(16 * cf1 + l15) * KS + q * 8];
#pragma unroll
    for (int f = 0; f < 15; f++) {
      bf16x8 bb = *(const bf16x8*)&sK[(16 * f + l15) * KS + q * 8];
      acc[0][f] = mfma_bf16(af0, bb, acc[0][f]);
      if (cf1 < 15) acc[1][f] = mfma_bf16(af1, bb, acc[1][f]);
    }
    __syncthreads();
    if (t < 15) SC_WRITE();
  }
#undef SC_LOAD
#undef SC_WRITE

  const float rs = 0.0322748612183951f;  // 1/sqrt(960)
  for (int ci = 0; ci < 2; ci++) {
    int cf = wid + 8 * ci;
    if (cf >= 15) continue;
    int cbase = 16 * cf;
    int s = qsc(cbase);
    float* pb = probs + (size_t)mod * PB1 +
                ((size_t)16 * qcum[s] + (size_t)bh * (16 << s)) * 240;
    int crow = cbase - qcum[s] + q * 4;
    for (int f = 0; f < 15; f++)
      for (int r = 0; r < 4; r++)
        atomicAdd(&pb[(size_t)(crow + r) * 240 + 16 * f + l15], acc[ci][f][r] * rs);
  }
}

// ============ InstanceNorm over (c,k) per (b,h), then softmax over k (240)
__global__ __launch_bounds__(256) void k_inorm_softmax(float* __restrict__ p0,
                                                       float* __restrict__ p1, int c4) {
  float* p = (blockIdx.z ? p1 : p0) + (size_t)blockIdx.x * c4 * 240;
  const int tid = threadIdx.x;
  const int tot = c4 * 240;
  float s = 0.f, s2 = 0.f;
  for (int idx = tid; idx < tot; idx += 256) {
    float v = p[idx];
    s += v; s2 += v * v;
  }
#pragma unroll
  for (int off = 32; off > 0; off >>= 1) {
    s += __shfl_xor(s, off);
    s2 += __shfl_xor(s2, off);
  }
  __shared__ float rsum[4], rsum2[4], smv[2];
  const int wid = tid >> 6, lane = tid & 63;
  if (lane == 0) { rsum[wid] = s; rsum2[wid] = s2; }
  __syncthreads();
  if (tid == 0) {
    float ts = rsum[0] + rsum[1] + rsum[2] + rsum[3];
    float ts2 = rsum2[0] + rsum2[1] + rsum2[2] + rsum2[3];
    float mean = ts / tot;
    float var = ts2 / tot - mean * mean;
    smv[0] = mean; smv[1] = rsqrtf(var + 1e-5f);
  }
  __syncthreads();
  const float mean = smv[0], rstd = smv[1];
  for (int c = wid; c < c4; c += 4) {
    float* row = p + (size_t)c * 240;
    float x[4]; float mx = -1e30f;
#pragma unroll
    for (int t = 0; t < 4; t++) {
      int k = lane + 64 * t;
      x[t] = (k < 240) ? (row[k] - mean) * rstd : -1e30f;
      mx = fmaxf(mx, x[t]);
    }
#pragma unroll
    for (int off = 32; off > 0; off >>= 1) mx = fmaxf(mx, __shfl_xor(mx, off));
    float e[4], sum = 0.f;
#pragma unroll
    for (int t = 0; t < 4; t++) {
      int k = lane + 64 * t;
      e[t] = (k < 240) ? expf(x[t] - mx) : 0.f;
      sum += e[t];
    }
#pragma unroll
    for (int off = 32; off > 0; off >>= 1) sum += __shfl_xor(sum, off);
    const float inv = 1.f / sum;
#pragma unroll
    for (int t = 0; t < 4; t++) {
      int k = lane + 64 * t;
      if (k < 240) row[k] = e[t] * inv;
    }
  }
}

// ============ PV, ALL scales fused: ctx[b,n, col(c)] = sum_k P[c,k] * V[bh,n,k], c=0..239
// One block per (128-n-block, bh, mod): stages V once, computes all 240 ctx channels.
// 8 waves x 16 n-rows each; acc[15] covers the 15 c-frags (scale boundaries 16-aligned).
__global__ __launch_bounds__(512) void k_pv_all(
    const float* __restrict__ probs, const bf16_t* __restrict__ V0,
    const bf16_t* __restrict__ V1, bf16_t* __restrict__ ctx0, bf16_t* __restrict__ ctx1) {
  const size_t PB1 = (size_t)B_ * H_ * 240 * 240;
  const int qcum[4] = {0, 16, 48, 112};
  const int chof[4] = {0, 64, 192, 448};
  const int bh = blockIdx.y, b = bh >> 2, h = bh & 3;
  const int mod = blockIdx.z;
  const int n0 = blockIdx.x * 128;
  const bf16_t* v = mod ? V0 : V1;         // cross-modal (matches old k_pv wiring)
  bf16_t* ctx = mod ? ctx1 : ctx0;
  const float* pb_all = probs + (size_t)mod * PB1;
  const int tid = threadIdx.x, lane = tid & 63, wid = tid >> 6;  // wid 0..7
  const int l15 = lane & 15, q = lane >> 4;
  __shared__ bf16_t sV[128 * KS];
  __shared__ bf16_t sP[240 * KS];
  const f32x4 fz = {0.f, 0.f, 0.f, 0.f};
  f32x4 acc[15];
  for (int f = 0; f < 15; f++) acc[f] = fz;
  const bf16_t* vrow = v + ((size_t)bh * N_ + n0) * 240;
  for (int k0 = 0; k0 < 256; k0 += 32) {
    __syncthreads();
    {  // V uint4: 128 rows x 4 col-groups = 512 items, one per thread
      int r = tid >> 2, g = tid & 3, k = k0 + g * 8;
      if (k < 240) *(uint4*)&sV[r * KS + g * 8] = *(const uint4*)(vrow + (size_t)r * 240 + k);
      else *(uint4*)&sV[r * KS + g * 8] = make_uint4(0u, 0u, 0u, 0u);
    }
    for (int idx = tid; idx < 1920; idx += 512) {  // P fp32 -> bf16, 240 rows x 8 groups
      int cc = idx >> 3, cg = idx & 7, k = k0 + cg * 4;
      if (k < 240) {
        int s = qsc(cc);
        const float* prow = pb_all +
            ((size_t)16 * qcum[s] + (size_t)bh * (16 << s) + (cc - qcum[s])) * 240;
        stpk4(&sP[cc * KS + cg * 4], *(const float4*)(prow + k));
      } else {
        stz8(&sP[cc * KS + cg * 4]);
      }
    }
    __syncthreads();
    bf16x8 a = *(const bf16x8*)&sV[(wid * 16 + l15) * KS + q * 8];
#pragma unroll
    for (int f = 0; f < 15; f++) {
      bf16x8 bb = *(const bf16x8*)&sP[(16 * f + l15) * KS + q * 8];
      acc[f] = mfma_bf16(a, bb, acc[f]);
    }
  }
  // write: n-row = n0 + 16*wid + q*4 + r; channel = chof[s] + h*(16<<s) + (16f+l15-qcum[s])
  for (int f = 0; f < 15; f++) {
    int s = qsc(16 * f);
    int colbase = chof[s] + h * (16 << s) + 16 * f - qcum[s];
    for (int r = 0; r < 4; r++) {
      int mm = 16 * wid + q * 4 + r;
      ctx[((size_t)b * N_ + n0 + mm) * 960 + colbase + l15] = (bf16_t)acc[f][r];
    }
  }
}

// ============ out[b,n,obase+d] = sum_c ctx[b,n,chof+c] * Wob[d,c]   (fp32 out)
template <int CS>
__global__ __launch_bounds__(256) void k_wout(
    const bf16_t* __restrict__ c0p, const bf16_t* __restrict__ w0, int ob0,
    const bf16_t* __restrict__ c1p, const bf16_t* __restrict__ w1, int ob1,
    float* __restrict__ out, int chof) {
  constexpr int DT = (CS < 128) ? CS : 128;
  constexpr int NF = DT / 16;
  constexpr int DB = CS / DT;
  const int mod = blockIdx.z / DB, dch = blockIdx.z % DB;
  const bf16_t* ctx = mod ? c1p : c0p;
  const bf16_t* w = mod ? w1 : w0;
  const int obase = (mod ? ob1 : ob0) + dch * DT;
  const int m0 = blockIdx.x * 128;
  const int b = m0 >> 12, n0 = m0 & 4095;
  const int tid = threadIdx.x, lane = tid & 63, wid = tid >> 6;
  const int l15 = lane & 15, q = lane >> 4;
  __shared__ bf16_t sA[128 * KS];
  __shared__ bf16_t sB[DT * KS];
  const f32x4 fz = {0.f, 0.f, 0.f, 0.f};
  f32x4 acc[2][NF];
  for (int i = 0; i < 2; i++) for (int f = 0; f < NF; f++) acc[i][f] = fz;
  const bf16_t* arow = ctx + ((size_t)b * N_ + n0) * 960 + chof;
  const bf16_t* wb = w + (size_t)dch * DT * CS;
  for (int k0 = 0; k0 < CS; k0 += 32) {
    __syncthreads();
    for (int idx = tid; idx < 512; idx += 256) {  // ctx uint4
      int r = idx >> 2, g = idx & 3, k = k0 + g * 8;
      *(uint4*)&sA[r * KS + g * 8] = *(const uint4*)(arow + (size_t)r * 960 + k);
    }
    for (int idx = tid; idx < DT * 4; idx += 256) {  // W uint4 (bf16 pre-converted)
      int dd = idx >> 2, g = idx & 3, k = k0 + g * 8;
      *(uint4*)&sB[dd * KS + g * 8] = *(const uint4*)(wb + (size_t)dd * CS + k);
    }
    __syncthreads();
    const bf16_t* ap = &sA[(wid * 32 + l15) * KS + q * 8];
    bf16x8 a0 = *(const bf16x8*)ap;
    bf16x8 a1 = *(const bf16x8*)(ap + 16 * KS);
    for (int f = 0; f < NF; f++) {
      bf16x8 bb = *(const bf16x8*)&sB[(16 * f + l15) * KS + q * 8];
      acc[0][f] = mfma_bf16(a0, bb, acc[0][f]);
      acc[1][f] = mfma_bf16(a1, bb, acc[1][f]);
    }
  }
  float* orow = out + ((size_t)b * N_ + n0) * 1920 + obase;
  for (int i = 0; i < 2; i++)
    for (int f = 0; f < NF; f++)
      for (int r = 0; r < 4; r++) {
        int mm = wid * 32 + 16 * i + q * 4 + r;
        orow[(size_t)mm * 1920 + 16 * f + l15] = acc[i][f][r];
      }
}

extern "C" void kernel_launch(void* const* d_in, const int* in_sizes, int n_in,
                              void* d_out, int out_size, void* d_ws, size_t ws_size,
                              hipStream_t stream) {
  (void)in_sizes; (void)n_in; (void)out_size; (void)ws_size;
  const float* emb[2][4];
  const float* wq[2][4];
  const float* wo[2][4];
  for (int s = 0; s < 4; s++) {
    emb[0][s] = (const float*)d_in[2 * s];
    emb[1][s] = (const float*)d_in[2 * s + 1];
    wq[0][s] = (const float*)d_in[10 + 4 * s];
    wq[1][s] = (const float*)d_in[11 + 4 * s];
    wo[0][s] = (const float*)d_in[12 + 4 * s];
    wo[1][s] = (const float*)d_in[13 + 4 * s];
  }
  const float* emb_all = (const float*)d_in[8];
  const float* emb_alld = (const float*)d_in[9];
  const float* wkp = (const float*)d_in[26];
  const float* wvp = (const float*)d_in[27];
  const float* wkdp = (const float*)d_in[28];
  const float* wvdp = (const float*)d_in[29];
  float* out = (float*)d_out;

  // ws layout: [Kt0 Kt1 V0 V1 Q0/ctx0 Q1/ctx1 : bf16, 6*KV1] [probs fp32 2*PB1] [Wkvb][Wob]
  // Q region additionally hosts G (kvsplit bf16) before proj_q runs.
  bf16_t* w16 = (bf16_t*)d_ws;
  const size_t KV1 = (size_t)B_ * H_ * N_ * 240;  // 15,728,640
  const size_t PB1 = (size_t)B_ * H_ * 240 * 240;
  bf16_t* Kt0 = w16;
  bf16_t* Kt1 = w16 + KV1;
  bf16_t* V0 = w16 + 2 * KV1;
  bf16_t* V1 = w16 + 3 * KV1;
  bf16_t* Qb = w16 + 4 * KV1;              // G, then Qt, then ctx
  float* probs = (float*)(w16 + 6 * KV1);
  bf16_t* Wkvb = (bf16_t*)(probs + 2 * PB1);
  bf16_t* Wob = Wkvb + 230400;
  const int qcum[4] = {0, 16, 48, 112};
  const int chof[4] = {0, 64, 192, 448};
  const int soff[4] = {0, 4096, 20480, 86016};
  const dim3 blk(256);

  k_prep_w<<<dim3(256), blk, 0, stream>>>(wkp, wvp, wkdp, wvdp,
      wo[0][0], wo[0][1], wo[0][2], wo[0][3], wo[1][0], wo[1][1], wo[1][2], wo[1][3],
      Wkvb, Wob);
  hipMemsetAsync(probs, 0, 2 * PB1 * sizeof(float), stream);

  // --- kvsplit prepass: G (bf16, [mod][bh][n][240]) into the Q region ---
  k_kvsplit<<<dim3(2048), blk, 0, stream>>>(emb_all, emb_alld, Qb);
  // --- K/V projections (merged K+V per modality; K transposed; 512-thread blocks) ---
  k_proj_kv<<<dim3(B_ * H_ * N_ / 128, 2), dim3(512), 0, stream>>>(
      Qb, Wkvb, Kt0, V0, Kt1, V1);
  // --- Q projections (overwrite G with Qt; G is dead after proj_kv) ---
  for (int s = 0; s < 4; s++) {
    bf16_t* q0 = Qb + (size_t)B_ * H_ * N_ * qcum[s];
    bf16_t* q1 = q0 + KV1;
    dim3 g(B_ * N_ / 128, H_, 2);
    switch (s) {
      case 0: k_proj_q<16><<<g, blk, 0, stream>>>(emb[0][s], wq[0][s], q0, emb[1][s], wq[1][s], q1); break;
      case 1: k_proj_q<32><<<g, blk, 0, stream>>>(emb[0][s], wq[0][s], q0, emb[1][s], wq[1][s], q1); break;
      case 2: k_proj_q<64><<<g, blk, 0, stream>>>(emb[0][s], wq[0][s], q0, emb[1][s], wq[1][s], q1); break;
      case 3: k_proj_q<128><<<g, blk, 0, stream>>>(emb[0][s], wq[0][s], q0, emb[1][s], wq[1][s], q1); break;
    }
  }
  // --- scores, all scales fused; 8 n-chunks (halved atomic traffic) ---
  k_scores_all<<<dim3(B_ * H_, 16), dim3(512), 0, stream>>>(Qb, Kt0, Kt1, probs);
  // --- InstanceNorm + softmax ---
  for (int s = 0; s < 4; s++) {
    float* p0 = probs + (size_t)B_ * H_ * qcum[s] * 240;
    float* p1 = p0 + PB1;
    k_inorm_softmax<<<dim3(B_ * H_, 1, 2), blk, 0, stream>>>(p0, p1, 16 << s);
  }
  // --- PV, all scales fused (optical uses Vd=V1, DSM uses V0); ctx overlays Q region ---
  k_pv_all<<<dim3(N_ / 128, B_ * H_, 2), dim3(512), 0, stream>>>(
      probs, V0, V1, Qb, Qb + KV1);
  // --- output projection (bf16 weights) ---
  for (int s = 0; s < 4; s++) {
    const bf16_t* cx0 = Qb;
    const bf16_t* cx1 = Qb + KV1;
    const bf16_t* w0 = Wob + soff[s];
    const bf16_t* w1 = Wob + 348160 + soff[s];
    const int cs = 64 << s;
    const int db = (cs < 128) ? 1 : cs / 128;
    dim3 g(B_ * N_ / 128, 1, 2 * db);
    switch (s) {
      case 0: k_wout<64><<<g, blk, 0, stream>>>(cx0, w0, chof[s], cx1, w1, 960 + chof[s], out, chof[s]); break;
      case 1: k_wout<128><<<g, blk, 0, stream>>>(cx0, w0, chof[s], cx1, w1, 960 + chof[s], out, chof[s]); break;
      case 2: k_wout<256><<<g, blk, 0, stream>>>(cx0, w0, chof[s], cx1, w1, 960 + chof[s], out, chof[s]); break;
      case 3: k_wout<512><<<g, blk, 0, stream>>>(cx0, w0, chof[s], cx1, w1, 960 + chof[s], out, chof[s]); break;
    }
  }
}